// Round 5
// baseline (339.885 us; speedup 1.0000x reference)
//
#include <hip/hip_runtime.h>
#include <math.h>

// Problem constants (match reference setup_inputs)
#define BN     2
#define QN     4096
#define LN     1024
#define TOPKN  128
#define PI_F   3.14159265358979323846f

// ln(12.8)/7 and ln(3.2)/7 — omegas = 10*exp(i*K), matches jnp.logspace to ~1e-7 rel
#define K_OM0  0.3642064529893673
#define K_OM1  0.1661644014008115

typedef __attribute__((ext_vector_type(8))) short  s16x8;
typedef __attribute__((ext_vector_type(4))) float  f32x4;

__device__ __forceinline__ unsigned short f2bf(float f) {
    unsigned int u = __float_as_uint(f);
    u = (u + 0x7FFFu + ((u >> 16) & 1u)) >> 16;   // RNE
    return (unsigned short)u;
}

// ---------------------------------------------------------------------------
// Kernel 0: transpose+cvt all GEMM weights to bf16 wT[n][k] (k-contiguous).
// ---------------------------------------------------------------------------
__global__ __launch_bounds__(256) void transpose_all(
    const float* __restrict__ outW, const float* __restrict__ bandW,
    const float* __restrict__ modW, const float* __restrict__ hvW,
    const float* __restrict__ kvW, const float* __restrict__ queryW,
    const float* __restrict__ qW,
    unsigned short* __restrict__ outT, unsigned short* __restrict__ bandT,
    unsigned short* __restrict__ modT, unsigned short* __restrict__ hvT,
    unsigned short* __restrict__ kvT, unsigned short* __restrict__ queryT,
    unsigned short* __restrict__ qT)
{
    int bid = blockIdx.x, t = threadIdx.x;
    const float* src; unsigned short* dst; int K, N, lt;
    if      (bid < 32)  { src = outW;   dst = outT;   K = 128; N = 256; lt = bid; }
    else if (bid < 64)  { src = bandW;  dst = bandT;  K = 128; N = 256; lt = bid - 32; }
    else if (bid < 192) { src = modW;   dst = modT;   K = 512; N = 256; lt = bid - 64; }
    else if (bid < 256) { src = hvW;    dst = hvT;    K = 256; N = 256; lt = bid - 192; }
    else if (bid < 320) { src = kvW;    dst = kvT;    K = 256; N = 256; lt = bid - 256; }
    else if (bid < 336) { src = queryW; dst = queryT; K = 64;  N = 256; lt = bid - 320; }
    else                { src = qW;     dst = qT;     K = 256; N = 128; lt = bid - 336; }
    int tk = K >> 5;
    int kt = lt % tk, nt = lt / tk;
    int k0 = kt * 32, n0 = nt * 32;
    __shared__ float tile[32][33];
    int tx = t & 31, ty = t >> 5;       // 32 x 8
    #pragma unroll
    for (int r = 0; r < 4; r++)
        tile[ty + 8 * r][tx] = src[(k0 + ty + 8 * r) * N + n0 + tx];
    __syncthreads();
    #pragma unroll
    for (int r = 0; r < 4; r++)
        dst[(n0 + ty + 8 * r) * K + k0 + tx] = f2bf(tile[tx][ty + 8 * r]);
}

// ---------------------------------------------------------------------------
// Kernel 1: kv = tokens @ kv_W via MFMA (32 rows/block).
// K cols (0..127) -> kf[b][l][128] row-major fp32.
// V cols (128..255) -> vt[b][j][LN] transposed fp32 (for coalesced o·V).
// ---------------------------------------------------------------------------
__global__ __launch_bounds__(256) void kv_mfma(
    const float* __restrict__ tokens, const unsigned short* __restrict__ kvT,
    float* __restrict__ kf, float* __restrict__ vt)
{
    int l0 = blockIdx.x * 32;
    int t = threadIdx.x;
    __shared__ __align__(16) unsigned short tok_bf[32 * 264];
    #pragma unroll
    for (int i = 0; i < 32; i++)
        tok_bf[i * 264 + t] = f2bf(tokens[(l0 + i) * 256 + t]);
    __syncthreads();
    int w = t >> 6, lane = t & 63, quad = lane >> 4, l16 = lane & 15;
    int m0 = (w >> 1) * 16, n0 = (w & 1) * 128;
    f32x4 acc[8];
    #pragma unroll
    for (int s = 0; s < 8; s++) acc[s] = (f32x4){0.f, 0.f, 0.f, 0.f};
    #pragma unroll
    for (int kt = 0; kt < 8; kt++) {
        s16x8 a = *(const s16x8*)&tok_bf[(m0 + l16) * 264 + kt * 32 + quad * 8];
        #pragma unroll
        for (int sub = 0; sub < 8; sub++) {
            s16x8 b = *(const s16x8*)&kvT[(size_t)(n0 + sub * 16 + l16) * 256 + kt * 32 + quad * 8];
            acc[sub] = __builtin_amdgcn_mfma_f32_16x16x32_bf16(a, b, acc[sub], 0, 0, 0);
        }
    }
    if (n0 == 0) {   // K half
        #pragma unroll
        for (int sub = 0; sub < 8; sub++)
            #pragma unroll
            for (int r = 0; r < 4; r++)
                kf[(size_t)(l0 + m0 + quad * 4 + r) * 128 + sub * 16 + l16] = acc[sub][r];
    } else {         // V half -> transposed
        #pragma unroll
        for (int sub = 0; sub < 8; sub++)
            #pragma unroll
            for (int r = 0; r < 4; r++) {
                int row = l0 + m0 + quad * 4 + r;
                int col = sub * 16 + l16;
                vt[(size_t)((row >> 10) * 128 + col) * LN + (row & 1023)] = acc[sub][r];
            }
    }
}

// ---------------------------------------------------------------------------
// Kernel 2: q pipeline via MFMA (32 queries/block) + layer gammas (folded in).
// ---------------------------------------------------------------------------
__global__ __launch_bounds__(256) void q_mfma(
    const float* __restrict__ x, const unsigned short* __restrict__ queryT,
    const float* __restrict__ query_b, const unsigned short* __restrict__ qT,
    float* __restrict__ qall, unsigned short* __restrict__ gamb)
{
    int p0 = blockIdx.x * 32;
    int t = threadIdx.x;
    __shared__ float sh_x[128];
    __shared__ __align__(16) unsigned short gam_bf[32 * 72];
    __shared__ __align__(16) unsigned short xq_bf[32 * 264];
    if (t < 128) sh_x[t] = x[p0 * 4 + t];
    __syncthreads();
    {
        int e0 = t * 8;
        int g = e0 >> 6;
        #pragma unroll
        for (int j = 0; j < 8; j++) {
            int f = (e0 + j) & 63;
            int c = f >> 4, jj = f & 15, oi = jj & 7;
            float om = (float)(10.0 * exp((double)oi * K_OM0));
            float arg = PI_F * sh_x[g * 4 + c] * om;
            gam_bf[g * 72 + f] = f2bf((jj < 8) ? sinf(arg) : cosf(arg));
        }
    }
    // layer gammas for these 32 queries -> global (batch-independent)
    #pragma unroll
    for (int l = 0; l < 2; l++) {
        int e0 = t * 8;
        int g = e0 >> 6;
        double kom = l ? K_OM1 : K_OM0;
        #pragma unroll
        for (int j = 0; j < 8; j++) {
            int f = (e0 + j) & 63;
            int c = f >> 4, jj = f & 15, oi = jj & 7;
            float om = (float)(10.0 * exp((double)oi * kom));
            float arg = PI_F * sh_x[g * 4 + c] * om;
            gamb[(size_t)(l * QN + p0 + g) * 64 + f] = f2bf((jj < 8) ? sinf(arg) : cosf(arg));
        }
    }
    __syncthreads();
    int w = t >> 6, lane = t & 63, quad = lane >> 4, l16 = lane & 15;
    int m0 = (w >> 1) * 16;
    {
        int n0 = (w & 1) * 128;
        f32x4 acc[8];
        #pragma unroll
        for (int s = 0; s < 8; s++) acc[s] = (f32x4){0.f, 0.f, 0.f, 0.f};
        #pragma unroll
        for (int kt = 0; kt < 2; kt++) {
            s16x8 a = *(const s16x8*)&gam_bf[(m0 + l16) * 72 + kt * 32 + quad * 8];
            #pragma unroll
            for (int sub = 0; sub < 8; sub++) {
                s16x8 b = *(const s16x8*)&queryT[(n0 + sub * 16 + l16) * 64 + kt * 32 + quad * 8];
                acc[sub] = __builtin_amdgcn_mfma_f32_16x16x32_bf16(a, b, acc[sub], 0, 0, 0);
            }
        }
        #pragma unroll
        for (int sub = 0; sub < 8; sub++) {
            int col = n0 + sub * 16 + l16;
            float bias = query_b[col];
            #pragma unroll
            for (int r = 0; r < 4; r++)
                xq_bf[(m0 + quad * 4 + r) * 264 + col] = f2bf(fmaxf(acc[sub][r] + bias, 0.f));
        }
    }
    __syncthreads();
    {
        int n0 = (w & 1) * 64;
        f32x4 acc[4];
        #pragma unroll
        for (int s = 0; s < 4; s++) acc[s] = (f32x4){0.f, 0.f, 0.f, 0.f};
        #pragma unroll
        for (int kt = 0; kt < 8; kt++) {
            s16x8 a = *(const s16x8*)&xq_bf[(m0 + l16) * 264 + kt * 32 + quad * 8];
            #pragma unroll
            for (int sub = 0; sub < 4; sub++) {
                s16x8 b = *(const s16x8*)&qT[(n0 + sub * 16 + l16) * 256 + kt * 32 + quad * 8];
                acc[sub] = __builtin_amdgcn_mfma_f32_16x16x32_bf16(a, b, acc[sub], 0, 0, 0);
            }
        }
        #pragma unroll
        for (int sub = 0; sub < 4; sub++)
            #pragma unroll
            for (int r = 0; r < 4; r++)
                qall[(size_t)(p0 + m0 + quad * 4 + r) * 128 + n0 + sub * 16 + l16] = acc[sub][r];
    }
}

// ---------------------------------------------------------------------------
// Kernel 3: attention. 4 queries/block, 2048 blocks (8 blocks/CU -> 32 w/CU).
// Sim: wave = (head, query-parity), lane holds keys {lane, lane+64}; in-wave
// softmax only. o·V: V transposed, attention weights zero-padded to 4-aligned
// window start -> aligned float4 streams.
// ---------------------------------------------------------------------------
__global__ __launch_bounds__(256) void attn_kernel(
    const float* __restrict__ x,
    const float* __restrict__ kf, const float* __restrict__ vt,
    const float* __restrict__ qall,
    const int* __restrict__ gDp, const int* __restrict__ gHp,
    const int* __restrict__ gWp, const int* __restrict__ gTp,
    unsigned short* __restrict__ o_bf)
{
    const int bid = blockIdx.x;
    const int b   = bid >> 10;
    const int q0  = (bid & 1023) * 4;
    const int t   = threadIdx.x;
    const int wid = t >> 6;
    const int lane = t & 63;

    __shared__ __align__(16) float q_s[4 * 128];
    __shared__ __align__(16) float attn_p[4][2][136];  // zero-padded windows
    __shared__ int sh_s[4];

    for (int i = t; i < 4 * 2 * 136; i += 256) ((float*)attn_p)[i] = 0.f;
    #pragma unroll
    for (int i = 0; i < 2; i++) q_s[t + 256 * i] = qall[(size_t)q0 * 128 + t + 256 * i];
    if (t < 4) {
        int gD = gDp[0], gH = gHp[0], gW = gWp[0], gT = gTp[0];
        float g0 = x[(q0 + t) * 4 + 0], g1 = x[(q0 + t) * 4 + 1];
        float g2 = x[(q0 + t) * 4 + 2], g3 = x[(q0 + t) * 4 + 3];
        int zi = (int)(g0 * (float)gD);
        int yi = (int)(g1 * (float)gH);
        int xi = (int)(g2 * (float)gW);
        int ti = (int)(g3 * (float)gT);
        int idx = ((ti * gD + zi) * gH + yi) * gW + xi;
        int Ng = gD * gH * gW * gT;
        float tt = (float)idx / (float)Ng;
        int s = (int)ceilf(tt * (float)LN - ((float)(TOPKN / 2) + 0.5f));
        sh_s[t] = min(max(s, 0), LN - TOPKN);
    }
    __syncthreads();

    // ---- sim + softmax, per-wave (head h, queries qpar+2i) ----
    const int h = wid & 1, qpar = wid >> 1;
    #pragma unroll
    for (int i = 0; i < 2; i++) {
        int g = qpar + 2 * i;
        int s = sh_s[g];
        const float* k0p = kf + (size_t)(b * LN + s + lane) * 128 + h * 64;
        const float* k1p = k0p + 64 * 128;
        const float* qp  = q_s + g * 128 + h * 64;
        float a0 = 0.f, a1 = 0.f;
        #pragma unroll
        for (int d4 = 0; d4 < 16; d4++) {
            float4 qv = *(const float4*)(qp + d4 * 4);
            float4 k0 = *(const float4*)(k0p + d4 * 4);
            float4 k1 = *(const float4*)(k1p + d4 * 4);
            a0 += qv.x * k0.x + qv.y * k0.y + qv.z * k0.z + qv.w * k0.w;
            a1 += qv.x * k1.x + qv.y * k1.y + qv.z * k1.z + qv.w * k1.w;
        }
        a0 *= 0.125f; a1 *= 0.125f;
        float m = fmaxf(a0, a1);
        #pragma unroll
        for (int off = 1; off < 64; off <<= 1) m = fmaxf(m, __shfl_xor(m, off));
        float e0 = expf(a0 - m), e1 = expf(a1 - m);
        float ss = e0 + e1;
        #pragma unroll
        for (int off = 1; off < 64; off <<= 1) ss += __shfl_xor(ss, off);
        float inv = 1.f / ss;
        int off4 = s & 3;
        attn_p[g][h][off4 + lane]      = e0 * inv;
        attn_p[g][h][off4 + 64 + lane] = e1 * inv;
    }
    __syncthreads();

    // ---- o = attn @ V : thread = (col j, query-half), aligned f4 streams ----
    const int j = t & 127, half = t >> 7, hh = j >> 6;
    #pragma unroll
    for (int gi = 0; gi < 2; gi++) {
        int g = half * 2 + gi;
        int s4 = sh_s[g] & ~3;
        const float* vp = vt + (size_t)(b * 128 + j) * LN + s4;
        const float* ap = attn_p[g][hh];
        float oa0 = 0.f, oa1 = 0.f;
        #pragma unroll 4
        for (int k4 = 0; k4 < 33; k4++) {
            float4 a4 = *(const float4*)(ap + k4 * 4);
            float4 v4 = *(const float4*)(vp + k4 * 4);
            oa0 += a4.x * v4.x + a4.y * v4.y;
            oa1 += a4.z * v4.z + a4.w * v4.w;
        }
        o_bf[(size_t)(b * QN + q0 + g) * 128 + j] = f2bf(oa0 + oa1);
    }
}

// ---------------------------------------------------------------------------
// Kernel 4: MFMA MLP. 16 rows/block, 512 threads (8 waves x 32 cols).
// ---------------------------------------------------------------------------
__global__ __launch_bounds__(512) void mlp_kernel(
    const unsigned short* __restrict__ o_bf, const unsigned short* __restrict__ gamb,
    const unsigned short* __restrict__ outT, const float* __restrict__ out_b,
    const unsigned short* __restrict__ bandT, const float* __restrict__ band_b,
    const unsigned short* __restrict__ modT, const float* __restrict__ mod_b,
    const unsigned short* __restrict__ hvT, const float* __restrict__ hv_b,
    const float* __restrict__ outl_W, const float* __restrict__ outl_b,
    float* __restrict__ out)
{
    const int r0 = blockIdx.x * 16;        // global rows (b*QN + q)
    const int t = threadIdx.x;
    const int wid = t >> 6, lane = t & 63;
    const int quad = lane >> 4, l16 = lane & 15;
    const int n0 = wid * 32;

    __shared__ __align__(16) unsigned short modu_lds[16 * 264];
    __shared__ __align__(16) unsigned short s01_lds[16 * 264];
    __shared__ float fin[128];

    // ---- modulation = o @ out_W + out_b (K=128) ----
    {
        f32x4 acc[2];
        #pragma unroll
        for (int s = 0; s < 2; s++) acc[s] = (f32x4){0.f, 0.f, 0.f, 0.f};
        #pragma unroll
        for (int kt = 0; kt < 4; kt++) {
            s16x8 a = *(const s16x8*)&o_bf[(size_t)(r0 + l16) * 128 + kt * 32 + quad * 8];
            #pragma unroll
            for (int sub = 0; sub < 2; sub++) {
                s16x8 bf = *(const s16x8*)&outT[(n0 + sub * 16 + l16) * 128 + kt * 32 + quad * 8];
                acc[sub] = __builtin_amdgcn_mfma_f32_16x16x32_bf16(a, bf, acc[sub], 0, 0, 0);
            }
        }
        #pragma unroll
        for (int sub = 0; sub < 2; sub++) {
            int col = n0 + sub * 16 + l16;
            float bias = out_b[col];
            #pragma unroll
            for (int r = 0; r < 4; r++)
                modu_lds[(quad * 4 + r) * 264 + col] = f2bf(acc[sub][r] + bias);
        }
    }
    __syncthreads();

    // ---- band + mod layers ----
    const int qrow0 = r0 & (QN - 1);
    float m0f[8];
    #pragma unroll
    for (int l = 0; l < 2; l++) {
        f32x4 acc1[2], acc2[2];
        #pragma unroll
        for (int s = 0; s < 2; s++) { acc1[s] = (f32x4){0.f,0.f,0.f,0.f}; acc2[s] = (f32x4){0.f,0.f,0.f,0.f}; }
        #pragma unroll
        for (int kt = 0; kt < 2; kt++) {
            s16x8 a = *(const s16x8*)&gamb[(size_t)(l * QN + qrow0 + l16) * 64 + kt * 32 + quad * 8];
            #pragma unroll
            for (int sub = 0; sub < 2; sub++) {
                s16x8 bf = *(const s16x8*)&bandT[(n0 + sub * 16 + l16) * 128 + l * 64 + kt * 32 + quad * 8];
                acc1[sub] = __builtin_amdgcn_mfma_f32_16x16x32_bf16(a, bf, acc1[sub], 0, 0, 0);
            }
        }
        #pragma unroll
        for (int kt = 0; kt < 8; kt++) {
            s16x8 a = *(const s16x8*)&modu_lds[l16 * 264 + kt * 32 + quad * 8];
            #pragma unroll
            for (int sub = 0; sub < 2; sub++) {
                s16x8 bf = *(const s16x8*)&modT[(size_t)(n0 + sub * 16 + l16) * 512 + l * 256 + kt * 32 + quad * 8];
                acc2[sub] = __builtin_amdgcn_mfma_f32_16x16x32_bf16(a, bf, acc2[sub], 0, 0, 0);
            }
        }
        #pragma unroll
        for (int sub = 0; sub < 2; sub++) {
            int col = n0 + sub * 16 + l16;
            float bb = band_b[l * 256 + col];
            float mb = mod_b[l * 256 + col];
            #pragma unroll
            for (int r = 0; r < 4; r++) {
                float hval = fmaxf(acc1[sub][r] + bb, 0.f);
                float mval = fmaxf(hval + acc2[sub][r] + mb, 0.f);
                if (l == 0) m0f[sub * 4 + r] = mval;
                else s01_lds[(quad * 4 + r) * 264 + col] = f2bf(m0f[sub * 4 + r] + mval);
            }
        }
    }
    __syncthreads();

    // ---- h_v1 = relu(s01 @ hv_W + hv_b) + scalar head ----
    {
        f32x4 acc[2];
        #pragma unroll
        for (int s = 0; s < 2; s++) acc[s] = (f32x4){0.f, 0.f, 0.f, 0.f};
        #pragma unroll
        for (int kt = 0; kt < 8; kt++) {
            s16x8 a = *(const s16x8*)&s01_lds[l16 * 264 + kt * 32 + quad * 8];
            #pragma unroll
            for (int sub = 0; sub < 2; sub++) {
                s16x8 bf = *(const s16x8*)&hvT[(size_t)(n0 + sub * 16 + l16) * 256 + kt * 32 + quad * 8];
                acc[sub] = __builtin_amdgcn_mfma_f32_16x16x32_bf16(a, bf, acc[sub], 0, 0, 0);
            }
        }
        float w0s[2], w1s[2], hb[2];
        #pragma unroll
        for (int sub = 0; sub < 2; sub++) {
            int col = n0 + sub * 16 + l16;
            w0s[sub] = outl_W[col];
            w1s[sub] = outl_W[256 + col];
            hb[sub]  = hv_b[col];
        }
        #pragma unroll
        for (int r = 0; r < 4; r++) {
            float pv = 0.f;
            #pragma unroll
            for (int sub = 0; sub < 2; sub++) {
                float hvv = fmaxf(acc[sub][r] + hb[sub], 0.f);
                pv += m0f[sub * 4 + r] * w0s[sub] + hvv * w1s[sub];
            }
            #pragma unroll
            for (int off = 1; off < 16; off <<= 1) pv += __shfl_xor(pv, off);
            if (l16 == 0) fin[wid * 16 + quad * 4 + r] = pv;
        }
    }
    __syncthreads();
    if (t < 16) {
        float s = outl_b[0] + outl_b[1];
        #pragma unroll
        for (int w = 0; w < 8; w++) s += fin[w * 16 + t];
        out[r0 + t] = s;
    }
}

// ---------------------------------------------------------------------------
extern "C" void kernel_launch(void* const* d_in, const int* in_sizes, int n_in,
                              void* d_out, int out_size, void* d_ws, size_t ws_size,
                              hipStream_t stream)
{
    const float* x       = (const float*)d_in[0];
    const float* tokens  = (const float*)d_in[1];
    const float* query_W = (const float*)d_in[2];
    const float* query_b = (const float*)d_in[3];
    const float* q_W     = (const float*)d_in[4];
    const float* kv_W    = (const float*)d_in[5];
    const float* out_W   = (const float*)d_in[6];
    const float* out_b   = (const float*)d_in[7];
    const float* band_W  = (const float*)d_in[8];
    const float* band_b  = (const float*)d_in[9];
    const float* mod_W   = (const float*)d_in[10];
    const float* mod_b   = (const float*)d_in[11];
    const float* hv_W    = (const float*)d_in[12];
    const float* hv_b    = (const float*)d_in[13];
    const float* outl_W  = (const float*)d_in[14];
    const float* outl_b  = (const float*)d_in[15];
    const int*   gD      = (const int*)d_in[16];
    const int*   gH      = (const int*)d_in[17];
    const int*   gW      = (const int*)d_in[18];
    const int*   gT      = (const int*)d_in[19];

    float* ws   = (float*)d_ws;
    float* kf   = ws;                          // 2048*128 = 262144 floats
    float* vt   = ws + 262144;                 // 2*128*1024 = 262144 floats
    float* qall = ws + 524288;                 // 4096*128 = 524288 floats
    unsigned short* wb = (unsigned short*)(ws + 1048576);
    unsigned short* outT   = wb;               // 32768
    unsigned short* bandT  = wb + 32768;       // 32768
    unsigned short* modT   = wb + 65536;       // 131072
    unsigned short* hvT    = wb + 196608;      // 65536
    unsigned short* kvT    = wb + 262144;      // 65536
    unsigned short* queryT = wb + 327680;      // 16384
    unsigned short* qT     = wb + 344064;      // 32768
    unsigned short* o_bf   = wb + 376832;      // 8192*128 = 1048576
    unsigned short* gamb   = wb + 1425408;     // 2*4096*64 = 524288
    float* out = (float*)d_out;

    transpose_all<<<368, 256, 0, stream>>>(out_W, band_W, mod_W, hv_W, kv_W,
                                           query_W, q_W,
                                           outT, bandT, modT, hvT, kvT, queryT, qT);
    kv_mfma<<<64, 256, 0, stream>>>(tokens, kvT, kf, vt);
    q_mfma<<<128, 256, 0, stream>>>(x, queryT, query_b, qT, qall, gamb);
    attn_kernel<<<2048, 256, 0, stream>>>(x, kf, vt, qall, gD, gH, gW, gT, o_bf);
    mlp_kernel<<<512, 512, 0, stream>>>(o_bf, gamb,
        outT, out_b, bandT, band_b, modT, mod_b, hvT, hv_b,
        outl_W, outl_b, out);
}

// Round 6
// 201.619 us; speedup vs baseline: 1.6858x; 1.6858x over previous
//
#include <hip/hip_runtime.h>
#include <math.h>

// Problem constants (match reference setup_inputs)
#define BN     2
#define QN     4096
#define LN     1024
#define TOPKN  128
#define PI_F   3.14159265358979323846f

// ln(12.8)/7 and ln(3.2)/7 — omegas = 10*exp(i*K), matches jnp.logspace to ~1e-7 rel
#define K_OM0  0.3642064529893673
#define K_OM1  0.1661644014008115

typedef __attribute__((ext_vector_type(8))) short  s16x8;
typedef __attribute__((ext_vector_type(4))) float  f32x4;

__device__ __forceinline__ unsigned short f2bf(float f) {
    unsigned int u = __float_as_uint(f);
    u = (u + 0x7FFFu + ((u >> 16) & 1u)) >> 16;   // RNE
    return (unsigned short)u;
}

// ---------------------------------------------------------------------------
// Kernel 0: transpose+cvt all GEMM weights to bf16 wT[n][k] (k-contiguous).
// ---------------------------------------------------------------------------
__global__ __launch_bounds__(256) void transpose_all(
    const float* __restrict__ outW, const float* __restrict__ bandW,
    const float* __restrict__ modW, const float* __restrict__ hvW,
    const float* __restrict__ kvW, const float* __restrict__ queryW,
    const float* __restrict__ qW,
    unsigned short* __restrict__ outT, unsigned short* __restrict__ bandT,
    unsigned short* __restrict__ modT, unsigned short* __restrict__ hvT,
    unsigned short* __restrict__ kvT, unsigned short* __restrict__ queryT,
    unsigned short* __restrict__ qT)
{
    int bid = blockIdx.x, t = threadIdx.x;
    const float* src; unsigned short* dst; int K, N, lt;
    if      (bid < 32)  { src = outW;   dst = outT;   K = 128; N = 256; lt = bid; }
    else if (bid < 64)  { src = bandW;  dst = bandT;  K = 128; N = 256; lt = bid - 32; }
    else if (bid < 192) { src = modW;   dst = modT;   K = 512; N = 256; lt = bid - 64; }
    else if (bid < 256) { src = hvW;    dst = hvT;    K = 256; N = 256; lt = bid - 192; }
    else if (bid < 320) { src = kvW;    dst = kvT;    K = 256; N = 256; lt = bid - 256; }
    else if (bid < 336) { src = queryW; dst = queryT; K = 64;  N = 256; lt = bid - 320; }
    else                { src = qW;     dst = qT;     K = 256; N = 128; lt = bid - 336; }
    int tk = K >> 5;
    int kt = lt % tk, nt = lt / tk;
    int k0 = kt * 32, n0 = nt * 32;
    __shared__ float tile[32][33];
    int tx = t & 31, ty = t >> 5;       // 32 x 8
    #pragma unroll
    for (int r = 0; r < 4; r++)
        tile[ty + 8 * r][tx] = src[(k0 + ty + 8 * r) * N + n0 + tx];
    __syncthreads();
    #pragma unroll
    for (int r = 0; r < 4; r++)
        dst[(n0 + ty + 8 * r) * K + k0 + tx] = f2bf(tile[tx][ty + 8 * r]);
}

// ---------------------------------------------------------------------------
// Kernel 1: kv = tokens @ kv_W via MFMA (16 rows/block, 128 blocks).
// K cols -> kt[b][d][LN] (transposed via LDS tile, coalesced-ish writes).
// V cols -> vf[b][l][128] row-major (lane-contiguous for o·V).
// ---------------------------------------------------------------------------
__global__ __launch_bounds__(256) void kv_mfma(
    const float* __restrict__ tokens, const unsigned short* __restrict__ kvT,
    float* __restrict__ kt, float* __restrict__ vf)
{
    int l0 = blockIdx.x * 16;          // 0..2047
    int b  = l0 >> 10, lloc = l0 & 1023;
    int t = threadIdx.x;
    __shared__ __align__(16) unsigned short tok_bf[16 * 264];
    __shared__ __align__(16) float ktile[128][20];   // [d][l-local], pad 20
    #pragma unroll
    for (int i = 0; i < 16; i++)
        tok_bf[i * 264 + t] = f2bf(tokens[(size_t)(l0 + i) * 256 + t]);
    __syncthreads();
    int w = t >> 6, lane = t & 63, quad = lane >> 4, l16 = lane & 15;
    int n0 = w * 64;
    f32x4 acc[4];
    #pragma unroll
    for (int s = 0; s < 4; s++) acc[s] = (f32x4){0.f, 0.f, 0.f, 0.f};
    #pragma unroll
    for (int kt2 = 0; kt2 < 8; kt2++) {
        s16x8 a = *(const s16x8*)&tok_bf[l16 * 264 + kt2 * 32 + quad * 8];
        #pragma unroll
        for (int sub = 0; sub < 4; sub++) {
            s16x8 bf = *(const s16x8*)&kvT[(size_t)(n0 + sub * 16 + l16) * 256 + kt2 * 32 + quad * 8];
            acc[sub] = __builtin_amdgcn_mfma_f32_16x16x32_bf16(a, bf, acc[sub], 0, 0, 0);
        }
    }
    if (w < 2) {       // K half: cols 0..127 -> LDS tile for transpose
        #pragma unroll
        for (int sub = 0; sub < 4; sub++)
            #pragma unroll
            for (int r = 0; r < 4; r++)
                ktile[n0 + sub * 16 + l16][quad * 4 + r] = acc[sub][r];
    } else {           // V half -> row-major vf
        #pragma unroll
        for (int sub = 0; sub < 4; sub++)
            #pragma unroll
            for (int r = 0; r < 4; r++)
                vf[(size_t)(l0 + quad * 4 + r) * 128 + (n0 - 128) + sub * 16 + l16] = acc[sub][r];
    }
    __syncthreads();
    {   // write kt: thread pair per d-row, 16 floats each
        int d = t >> 1, half = t & 1;
        float4 u0 = *(const float4*)&ktile[d][half * 8];
        float4 u1 = *(const float4*)&ktile[d][half * 8 + 4];
        float* dst = kt + (size_t)(b * 128 + d) * LN + lloc + half * 8;
        *(float4*)dst = u0;
        *(float4*)(dst + 4) = u1;
    }
}

// ---------------------------------------------------------------------------
// Kernel 2: q pipeline via MFMA (32 queries/block) + layer gammas (folded in).
// ---------------------------------------------------------------------------
__global__ __launch_bounds__(256) void q_mfma(
    const float* __restrict__ x, const unsigned short* __restrict__ queryT,
    const float* __restrict__ query_b, const unsigned short* __restrict__ qT,
    float* __restrict__ qall, unsigned short* __restrict__ gamb)
{
    int p0 = blockIdx.x * 32;
    int t = threadIdx.x;
    __shared__ float sh_x[128];
    __shared__ __align__(16) unsigned short gam_bf[32 * 72];
    __shared__ __align__(16) unsigned short xq_bf[32 * 264];
    if (t < 128) sh_x[t] = x[p0 * 4 + t];
    __syncthreads();
    {
        int e0 = t * 8;
        int g = e0 >> 6;
        #pragma unroll
        for (int j = 0; j < 8; j++) {
            int f = (e0 + j) & 63;
            int c = f >> 4, jj = f & 15, oi = jj & 7;
            float om = (float)(10.0 * exp((double)oi * K_OM0));
            float arg = PI_F * sh_x[g * 4 + c] * om;
            gam_bf[g * 72 + f] = f2bf((jj < 8) ? sinf(arg) : cosf(arg));
        }
    }
    // layer gammas for these 32 queries -> global (batch-independent)
    #pragma unroll
    for (int l = 0; l < 2; l++) {
        int e0 = t * 8;
        int g = e0 >> 6;
        double kom = l ? K_OM1 : K_OM0;
        #pragma unroll
        for (int j = 0; j < 8; j++) {
            int f = (e0 + j) & 63;
            int c = f >> 4, jj = f & 15, oi = jj & 7;
            float om = (float)(10.0 * exp((double)oi * kom));
            float arg = PI_F * sh_x[g * 4 + c] * om;
            gamb[(size_t)(l * QN + p0 + g) * 64 + f] = f2bf((jj < 8) ? sinf(arg) : cosf(arg));
        }
    }
    __syncthreads();
    int w = t >> 6, lane = t & 63, quad = lane >> 4, l16 = lane & 15;
    int m0 = (w >> 1) * 16;
    {
        int n0 = (w & 1) * 128;
        f32x4 acc[8];
        #pragma unroll
        for (int s = 0; s < 8; s++) acc[s] = (f32x4){0.f, 0.f, 0.f, 0.f};
        #pragma unroll
        for (int kt = 0; kt < 2; kt++) {
            s16x8 a = *(const s16x8*)&gam_bf[(m0 + l16) * 72 + kt * 32 + quad * 8];
            #pragma unroll
            for (int sub = 0; sub < 8; sub++) {
                s16x8 b = *(const s16x8*)&queryT[(n0 + sub * 16 + l16) * 64 + kt * 32 + quad * 8];
                acc[sub] = __builtin_amdgcn_mfma_f32_16x16x32_bf16(a, b, acc[sub], 0, 0, 0);
            }
        }
        #pragma unroll
        for (int sub = 0; sub < 8; sub++) {
            int col = n0 + sub * 16 + l16;
            float bias = query_b[col];
            #pragma unroll
            for (int r = 0; r < 4; r++)
                xq_bf[(m0 + quad * 4 + r) * 264 + col] = f2bf(fmaxf(acc[sub][r] + bias, 0.f));
        }
    }
    __syncthreads();
    {
        int n0 = (w & 1) * 64;
        f32x4 acc[4];
        #pragma unroll
        for (int s = 0; s < 4; s++) acc[s] = (f32x4){0.f, 0.f, 0.f, 0.f};
        #pragma unroll
        for (int kt = 0; kt < 8; kt++) {
            s16x8 a = *(const s16x8*)&xq_bf[(m0 + l16) * 264 + kt * 32 + quad * 8];
            #pragma unroll
            for (int sub = 0; sub < 4; sub++) {
                s16x8 b = *(const s16x8*)&qT[(n0 + sub * 16 + l16) * 256 + kt * 32 + quad * 8];
                acc[sub] = __builtin_amdgcn_mfma_f32_16x16x32_bf16(a, b, acc[sub], 0, 0, 0);
            }
        }
        #pragma unroll
        for (int sub = 0; sub < 4; sub++)
            #pragma unroll
            for (int r = 0; r < 4; r++)
                qall[(size_t)(p0 + m0 + quad * 4 + r) * 128 + n0 + sub * 16 + l16] = acc[sub][r];
    }
}

// ---------------------------------------------------------------------------
// Kernel 3: attention. 4 queries/block, 2048 blocks (8 blocks/CU).
// Sim: K transposed -> lane-contiguous coalesced loads (lane = key),
// q[d] broadcast from LDS; softmax fully in-wave.
// o·V: V row-major, lane = col pair -> aligned float2 coalesced loads.
// ---------------------------------------------------------------------------
__global__ __launch_bounds__(256) void attn_kernel(
    const float* __restrict__ x,
    const float* __restrict__ kt, const float* __restrict__ vf,
    const float* __restrict__ qall,
    const int* __restrict__ gDp, const int* __restrict__ gHp,
    const int* __restrict__ gWp, const int* __restrict__ gTp,
    unsigned short* __restrict__ o_bf)
{
    const int bid = blockIdx.x;
    const int b   = bid >> 10;
    const int q0  = (bid & 1023) * 4;
    const int t   = threadIdx.x;
    const int wid = t >> 6;
    const int lane = t & 63;

    __shared__ __align__(16) float q_s[4 * 128];
    __shared__ __align__(16) float attn_T[4][256];   // [g][h*128 + key]
    __shared__ int sh_s[4];

    #pragma unroll
    for (int i = 0; i < 2; i++) q_s[t + 256 * i] = qall[(size_t)q0 * 128 + t + 256 * i];
    if (t < 4) {
        int gD = gDp[0], gH = gHp[0], gW = gWp[0], gT = gTp[0];
        float g0 = x[(q0 + t) * 4 + 0], g1 = x[(q0 + t) * 4 + 1];
        float g2 = x[(q0 + t) * 4 + 2], g3 = x[(q0 + t) * 4 + 3];
        int zi = (int)(g0 * (float)gD);
        int yi = (int)(g1 * (float)gH);
        int xi = (int)(g2 * (float)gW);
        int ti = (int)(g3 * (float)gT);
        int idx = ((ti * gD + zi) * gH + yi) * gW + xi;
        int Ng = gD * gH * gW * gT;
        float tt = (float)idx / (float)Ng;
        int s = (int)ceilf(tt * (float)LN - ((float)(TOPKN / 2) + 0.5f));
        sh_s[t] = min(max(s, 0), LN - TOPKN);
    }
    __syncthreads();

    // ---- sim + softmax: wave = (head h, query pair); lane = key ----
    const int h = wid & 1, qp2 = wid >> 1;
    #pragma unroll
    for (int i = 0; i < 2; i++) {
        int g = qp2 * 2 + i;
        int s = sh_s[g];
        const float* ktp = kt + (size_t)(b * 128 + h * 64) * LN + s + lane;
        const float* qrow = q_s + g * 128 + h * 64;
        float a0 = 0.f, a1 = 0.f;
        #pragma unroll 8
        for (int d = 0; d < 64; d++) {
            float qd = qrow[d];
            a0 += qd * ktp[d * LN];        // keys s+lane
            a1 += qd * ktp[d * LN + 64];   // keys s+64+lane
        }
        a0 *= 0.125f; a1 *= 0.125f;
        float m = fmaxf(a0, a1);
        #pragma unroll
        for (int off = 1; off < 64; off <<= 1) m = fmaxf(m, __shfl_xor(m, off));
        float e0 = expf(a0 - m), e1 = expf(a1 - m);
        float ss = e0 + e1;
        #pragma unroll
        for (int off = 1; off < 64; off <<= 1) ss += __shfl_xor(ss, off);
        float inv = 1.f / ss;
        attn_T[g][h * 128 + lane]      = e0 * inv;
        attn_T[g][h * 128 + 64 + lane] = e1 * inv;
    }
    __syncthreads();

    // ---- o = attn @ V : wave = query, lane = col pair (aligned float2) ----
    {
        int g = wid;
        int s = sh_s[g];
        const float* vp = vf + (size_t)(b * LN + s) * 128 + 2 * lane;
        const float* ap = attn_T[g] + (lane >> 5) * 128;   // head of col pair
        float oa0 = 0.f, oa1 = 0.f;
        #pragma unroll 8
        for (int k = 0; k < 128; k++) {
            float2 v2 = *(const float2*)(vp + (size_t)k * 128);
            float aw = ap[k];
            oa0 += aw * v2.x; oa1 += aw * v2.y;
        }
        unsigned int packed = (unsigned int)f2bf(oa0) | ((unsigned int)f2bf(oa1) << 16);
        *(unsigned int*)&o_bf[(size_t)(b * QN + q0 + g) * 128 + 2 * lane] = packed;
    }
}

// ---------------------------------------------------------------------------
// Kernel 4: MFMA MLP. 16 rows/block, 512 threads (8 waves x 32 cols).
// ---------------------------------------------------------------------------
__global__ __launch_bounds__(512) void mlp_kernel(
    const unsigned short* __restrict__ o_bf, const unsigned short* __restrict__ gamb,
    const unsigned short* __restrict__ outT, const float* __restrict__ out_b,
    const unsigned short* __restrict__ bandT, const float* __restrict__ band_b,
    const unsigned short* __restrict__ modT, const float* __restrict__ mod_b,
    const unsigned short* __restrict__ hvT, const float* __restrict__ hv_b,
    const float* __restrict__ outl_W, const float* __restrict__ outl_b,
    float* __restrict__ out)
{
    const int r0 = blockIdx.x * 16;        // global rows (b*QN + q)
    const int t = threadIdx.x;
    const int wid = t >> 6, lane = t & 63;
    const int quad = lane >> 4, l16 = lane & 15;
    const int n0 = wid * 32;

    __shared__ __align__(16) unsigned short modu_lds[16 * 264];
    __shared__ __align__(16) unsigned short s01_lds[16 * 264];
    __shared__ float fin[128];

    // ---- modulation = o @ out_W + out_b (K=128) ----
    {
        f32x4 acc[2];
        #pragma unroll
        for (int s = 0; s < 2; s++) acc[s] = (f32x4){0.f, 0.f, 0.f, 0.f};
        #pragma unroll
        for (int kt = 0; kt < 4; kt++) {
            s16x8 a = *(const s16x8*)&o_bf[(size_t)(r0 + l16) * 128 + kt * 32 + quad * 8];
            #pragma unroll
            for (int sub = 0; sub < 2; sub++) {
                s16x8 bf = *(const s16x8*)&outT[(n0 + sub * 16 + l16) * 128 + kt * 32 + quad * 8];
                acc[sub] = __builtin_amdgcn_mfma_f32_16x16x32_bf16(a, bf, acc[sub], 0, 0, 0);
            }
        }
        #pragma unroll
        for (int sub = 0; sub < 2; sub++) {
            int col = n0 + sub * 16 + l16;
            float bias = out_b[col];
            #pragma unroll
            for (int r = 0; r < 4; r++)
                modu_lds[(quad * 4 + r) * 264 + col] = f2bf(acc[sub][r] + bias);
        }
    }
    __syncthreads();

    // ---- band + mod layers ----
    const int qrow0 = r0 & (QN - 1);
    float m0f[8];
    #pragma unroll
    for (int l = 0; l < 2; l++) {
        f32x4 acc1[2], acc2[2];
        #pragma unroll
        for (int s = 0; s < 2; s++) { acc1[s] = (f32x4){0.f,0.f,0.f,0.f}; acc2[s] = (f32x4){0.f,0.f,0.f,0.f}; }
        #pragma unroll
        for (int kt = 0; kt < 2; kt++) {
            s16x8 a = *(const s16x8*)&gamb[(size_t)(l * QN + qrow0 + l16) * 64 + kt * 32 + quad * 8];
            #pragma unroll
            for (int sub = 0; sub < 2; sub++) {
                s16x8 bf = *(const s16x8*)&bandT[(n0 + sub * 16 + l16) * 128 + l * 64 + kt * 32 + quad * 8];
                acc1[sub] = __builtin_amdgcn_mfma_f32_16x16x32_bf16(a, bf, acc1[sub], 0, 0, 0);
            }
        }
        #pragma unroll
        for (int kt = 0; kt < 8; kt++) {
            s16x8 a = *(const s16x8*)&modu_lds[l16 * 264 + kt * 32 + quad * 8];
            #pragma unroll
            for (int sub = 0; sub < 2; sub++) {
                s16x8 bf = *(const s16x8*)&modT[(size_t)(n0 + sub * 16 + l16) * 512 + l * 256 + kt * 32 + quad * 8];
                acc2[sub] = __builtin_amdgcn_mfma_f32_16x16x32_bf16(a, bf, acc2[sub], 0, 0, 0);
            }
        }
        #pragma unroll
        for (int sub = 0; sub < 2; sub++) {
            int col = n0 + sub * 16 + l16;
            float bb = band_b[l * 256 + col];
            float mb = mod_b[l * 256 + col];
            #pragma unroll
            for (int r = 0; r < 4; r++) {
                float hval = fmaxf(acc1[sub][r] + bb, 0.f);
                float mval = fmaxf(hval + acc2[sub][r] + mb, 0.f);
                if (l == 0) m0f[sub * 4 + r] = mval;
                else s01_lds[(quad * 4 + r) * 264 + col] = f2bf(m0f[sub * 4 + r] + mval);
            }
        }
    }
    __syncthreads();

    // ---- h_v1 = relu(s01 @ hv_W + hv_b) + scalar head ----
    {
        f32x4 acc[2];
        #pragma unroll
        for (int s = 0; s < 2; s++) acc[s] = (f32x4){0.f, 0.f, 0.f, 0.f};
        #pragma unroll
        for (int kt = 0; kt < 8; kt++) {
            s16x8 a = *(const s16x8*)&s01_lds[l16 * 264 + kt * 32 + quad * 8];
            #pragma unroll
            for (int sub = 0; sub < 2; sub++) {
                s16x8 bf = *(const s16x8*)&hvT[(size_t)(n0 + sub * 16 + l16) * 256 + kt * 32 + quad * 8];
                acc[sub] = __builtin_amdgcn_mfma_f32_16x16x32_bf16(a, bf, acc[sub], 0, 0, 0);
            }
        }
        float w0s[2], w1s[2], hb[2];
        #pragma unroll
        for (int sub = 0; sub < 2; sub++) {
            int col = n0 + sub * 16 + l16;
            w0s[sub] = outl_W[col];
            w1s[sub] = outl_W[256 + col];
            hb[sub]  = hv_b[col];
        }
        #pragma unroll
        for (int r = 0; r < 4; r++) {
            float pv = 0.f;
            #pragma unroll
            for (int sub = 0; sub < 2; sub++) {
                float hvv = fmaxf(acc[sub][r] + hb[sub], 0.f);
                pv += m0f[sub * 4 + r] * w0s[sub] + hvv * w1s[sub];
            }
            #pragma unroll
            for (int off = 1; off < 16; off <<= 1) pv += __shfl_xor(pv, off);
            if (l16 == 0) fin[wid * 16 + quad * 4 + r] = pv;
        }
    }
    __syncthreads();
    if (t < 16) {
        float s = outl_b[0] + outl_b[1];
        #pragma unroll
        for (int w = 0; w < 8; w++) s += fin[w * 16 + t];
        out[r0 + t] = s;
    }
}

// ---------------------------------------------------------------------------
extern "C" void kernel_launch(void* const* d_in, const int* in_sizes, int n_in,
                              void* d_out, int out_size, void* d_ws, size_t ws_size,
                              hipStream_t stream)
{
    const float* x       = (const float*)d_in[0];
    const float* tokens  = (const float*)d_in[1];
    const float* query_W = (const float*)d_in[2];
    const float* query_b = (const float*)d_in[3];
    const float* q_W     = (const float*)d_in[4];
    const float* kv_W    = (const float*)d_in[5];
    const float* out_W   = (const float*)d_in[6];
    const float* out_b   = (const float*)d_in[7];
    const float* band_W  = (const float*)d_in[8];
    const float* band_b  = (const float*)d_in[9];
    const float* mod_W   = (const float*)d_in[10];
    const float* mod_b   = (const float*)d_in[11];
    const float* hv_W    = (const float*)d_in[12];
    const float* hv_b    = (const float*)d_in[13];
    const float* outl_W  = (const float*)d_in[14];
    const float* outl_b  = (const float*)d_in[15];
    const int*   gD      = (const int*)d_in[16];
    const int*   gH      = (const int*)d_in[17];
    const int*   gW      = (const int*)d_in[18];
    const int*   gT      = (const int*)d_in[19];

    float* ws   = (float*)d_ws;
    float* kt   = ws;                          // 2*128*1024 = 262144 floats
    float* vf   = ws + 262144;                 // 2*1024*128 = 262144 floats
    float* qall = ws + 524288;                 // 4096*128 = 524288 floats
    unsigned short* wb = (unsigned short*)(ws + 1048576);
    unsigned short* outT   = wb;               // 32768
    unsigned short* bandT  = wb + 32768;       // 32768
    unsigned short* modT   = wb + 65536;       // 131072
    unsigned short* hvT    = wb + 196608;      // 65536
    unsigned short* kvT    = wb + 262144;      // 65536
    unsigned short* queryT = wb + 327680;      // 16384
    unsigned short* qT     = wb + 344064;      // 32768
    unsigned short* o_bf   = wb + 376832;      // 8192*128 = 1048576
    unsigned short* gamb   = wb + 1425408;     // 2*4096*64 = 524288
    float* out = (float*)d_out;

    transpose_all<<<368, 256, 0, stream>>>(out_W, band_W, mod_W, hv_W, kv_W,
                                           query_W, q_W,
                                           outT, bandT, modT, hvT, kvT, queryT, qT);
    kv_mfma<<<128, 256, 0, stream>>>(tokens, kvT, kt, vf);
    q_mfma<<<128, 256, 0, stream>>>(x, queryT, query_b, qT, qall, gamb);
    attn_kernel<<<2048, 256, 0, stream>>>(x, kt, vf, qall, gD, gH, gW, gT, o_bf);
    mlp_kernel<<<512, 512, 0, stream>>>(o_bf, gamb,
        outT, out_b, bandT, band_b, modT, mod_b, hvT, hv_b,
        outl_W, outl_b, out);
}

// Round 7
// 188.418 us; speedup vs baseline: 1.8039x; 1.0701x over previous
//
#include <hip/hip_runtime.h>
#include <math.h>

// Problem constants (match reference setup_inputs)
#define BN     2
#define QN     4096
#define LN     1024
#define TOPKN  128
#define PI_F   3.14159265358979323846f

// ln(12.8)/7 and ln(3.2)/7 — omegas = 10*exp(i*K), matches jnp.logspace to ~1e-7 rel
#define K_OM0  0.3642064529893673
#define K_OM1  0.1661644014008115

typedef __attribute__((ext_vector_type(8))) short  s16x8;
typedef __attribute__((ext_vector_type(4))) float  f32x4;

__device__ __forceinline__ unsigned short f2bf(float f) {
    unsigned int u = __float_as_uint(f);
    u = (u + 0x7FFFu + ((u >> 16) & 1u)) >> 16;   // RNE
    return (unsigned short)u;
}

// ---------------------------------------------------------------------------
// Launch 1: prep. blockIdx dispatch:
//   [0,128)   kv path: kvf = tokens@kv_W via MFMA, kv_W self-staged (LDS bf16
//             B-tiles, k-chunked). K -> kt[b][d][L] transposed; V -> vf[b][l][128].
//   [128,256) q path: gamma -> xq -> q, query_W/q_W self-staged.
//   [256,512) transpose out/band/mod/hv to bf16 wT[n][k] for the fused kernel.
// ---------------------------------------------------------------------------
struct KvSmem {
    unsigned short tok_bf[16 * 264];
    unsigned short stage[256 * 40];   // B-tile [n][kchunk], pad 40 (16B-aligned rows)
    float ktile[128][20];
};
struct QSmem {
    float sh_x[128];
    unsigned short gam_bf[32 * 72];
    unsigned short xq_bf[32 * 264];
    unsigned short stage[256 * 40];
};
struct TrSmem { float tile[32][33]; };
union PrepSmem { KvSmem kv; QSmem q; TrSmem tr; };

__global__ __launch_bounds__(256) void prep_kernel(
    const float* __restrict__ tokens, const float* __restrict__ kv_W,
    const float* __restrict__ x, const float* __restrict__ query_W,
    const float* __restrict__ query_b, const float* __restrict__ q_W,
    const float* __restrict__ outW, const float* __restrict__ bandW,
    const float* __restrict__ modW, const float* __restrict__ hvW,
    float* __restrict__ kt, float* __restrict__ vf, float* __restrict__ qall,
    unsigned short* __restrict__ outT, unsigned short* __restrict__ bandT,
    unsigned short* __restrict__ modT, unsigned short* __restrict__ hvT)
{
    __shared__ __align__(16) PrepSmem sm;
    const int bid = blockIdx.x, t = threadIdx.x;

    if (bid < 128) {
        // ------------------------- kv path -------------------------
        int l0 = bid * 16;
        int b = l0 >> 10, lloc = l0 & 1023;
        #pragma unroll
        for (int i = 0; i < 16; i++)
            sm.kv.tok_bf[i * 264 + t] = f2bf(tokens[(size_t)(l0 + i) * 256 + t]);
        int w = t >> 6, lane = t & 63, quad = lane >> 4, l16 = lane & 15;
        int n0 = w * 64;
        f32x4 acc[4];
        #pragma unroll
        for (int s = 0; s < 4; s++) acc[s] = (f32x4){0.f, 0.f, 0.f, 0.f};
        for (int kc = 0; kc < 8; kc++) {
            __syncthreads();
            #pragma unroll
            for (int i = 0; i < 32; i++)
                sm.kv.stage[t * 40 + i] = f2bf(kv_W[(size_t)(kc * 32 + i) * 256 + t]);
            __syncthreads();
            s16x8 a = *(const s16x8*)&sm.kv.tok_bf[l16 * 264 + kc * 32 + quad * 8];
            #pragma unroll
            for (int sub = 0; sub < 4; sub++) {
                s16x8 bfr = *(const s16x8*)&sm.kv.stage[(n0 + sub * 16 + l16) * 40 + quad * 8];
                acc[sub] = __builtin_amdgcn_mfma_f32_16x16x32_bf16(a, bfr, acc[sub], 0, 0, 0);
            }
        }
        if (w < 2) {       // K half: cols 0..127 -> LDS tile for transpose
            #pragma unroll
            for (int sub = 0; sub < 4; sub++)
                #pragma unroll
                for (int r = 0; r < 4; r++)
                    sm.kv.ktile[n0 + sub * 16 + l16][quad * 4 + r] = acc[sub][r];
        } else {           // V half -> row-major vf
            #pragma unroll
            for (int sub = 0; sub < 4; sub++)
                #pragma unroll
                for (int r = 0; r < 4; r++)
                    vf[(size_t)(l0 + quad * 4 + r) * 128 + (n0 - 128) + sub * 16 + l16] = acc[sub][r];
        }
        __syncthreads();
        {   // write kt transposed: thread pair per d-row
            int d = t >> 1, half = t & 1;
            float4 u0 = *(const float4*)&sm.kv.ktile[d][half * 8];
            float4 u1 = *(const float4*)&sm.kv.ktile[d][half * 8 + 4];
            float* dst = kt + (size_t)(b * 128 + d) * LN + lloc + half * 8;
            *(float4*)dst = u0;
            *(float4*)(dst + 4) = u1;
        }
    } else if (bid < 256) {
        // ------------------------- q path -------------------------
        int p0 = (bid - 128) * 32;
        if (t < 128) sm.q.sh_x[t] = x[p0 * 4 + t];
        __syncthreads();
        {   // gamma (query-scale omegas)
            int e0 = t * 8;
            int g = e0 >> 6;
            #pragma unroll
            for (int j = 0; j < 8; j++) {
                int f = (e0 + j) & 63;
                int c = f >> 4, jj = f & 15, oi = jj & 7;
                float om = (float)(10.0 * exp((double)oi * K_OM0));
                float arg = PI_F * sm.q.sh_x[g * 4 + c] * om;
                sm.q.gam_bf[g * 72 + f] = f2bf((jj < 8) ? sinf(arg) : cosf(arg));
            }
        }
        int w = t >> 6, lane = t & 63, quad = lane >> 4, l16 = lane & 15;
        int m0 = (w >> 1) * 16;
        {   // stage 1: xq = relu(gamma @ query_W + b), query_W self-staged (2 chunks)
            int n0a = (w & 1) * 128;
            f32x4 acc[8];
            #pragma unroll
            for (int s = 0; s < 8; s++) acc[s] = (f32x4){0.f, 0.f, 0.f, 0.f};
            for (int kc = 0; kc < 2; kc++) {
                __syncthreads();
                #pragma unroll
                for (int i = 0; i < 32; i++)
                    sm.q.stage[t * 40 + i] = f2bf(query_W[(size_t)(kc * 32 + i) * 256 + t]);
                __syncthreads();
                s16x8 a = *(const s16x8*)&sm.q.gam_bf[(m0 + l16) * 72 + kc * 32 + quad * 8];
                #pragma unroll
                for (int sub = 0; sub < 8; sub++) {
                    s16x8 bfr = *(const s16x8*)&sm.q.stage[(n0a + sub * 16 + l16) * 40 + quad * 8];
                    acc[sub] = __builtin_amdgcn_mfma_f32_16x16x32_bf16(a, bfr, acc[sub], 0, 0, 0);
                }
            }
            #pragma unroll
            for (int sub = 0; sub < 8; sub++) {
                int col = n0a + sub * 16 + l16;
                float bias = query_b[col];
                #pragma unroll
                for (int r = 0; r < 4; r++)
                    sm.q.xq_bf[(m0 + quad * 4 + r) * 264 + col] = f2bf(fmaxf(acc[sub][r] + bias, 0.f));
            }
        }
        {   // stage 2: q = xq @ q_W, q_W self-staged (8 chunks)
            int n0b = (w & 1) * 64;
            f32x4 acc2[4];
            #pragma unroll
            for (int s = 0; s < 4; s++) acc2[s] = (f32x4){0.f, 0.f, 0.f, 0.f};
            for (int kc = 0; kc < 8; kc++) {
                __syncthreads();
                #pragma unroll
                for (int i = 0; i < 16; i++) {
                    int e = i * 256 + t;
                    int k = e >> 7, n = e & 127;
                    sm.q.stage[n * 40 + k] = f2bf(q_W[(size_t)(kc * 32 + k) * 128 + n]);
                }
                __syncthreads();
                s16x8 a = *(const s16x8*)&sm.q.xq_bf[(m0 + l16) * 264 + kc * 32 + quad * 8];
                #pragma unroll
                for (int sub = 0; sub < 4; sub++) {
                    s16x8 bfr = *(const s16x8*)&sm.q.stage[(n0b + sub * 16 + l16) * 40 + quad * 8];
                    acc2[sub] = __builtin_amdgcn_mfma_f32_16x16x32_bf16(a, bfr, acc2[sub], 0, 0, 0);
                }
            }
            #pragma unroll
            for (int sub = 0; sub < 4; sub++)
                #pragma unroll
                for (int r = 0; r < 4; r++)
                    qall[(size_t)(p0 + m0 + quad * 4 + r) * 128 + n0b + sub * 16 + l16] = acc2[sub][r];
        }
    } else {
        // --------------------- transpose path ---------------------
        int bid2 = bid - 256;
        const float* src; unsigned short* dst; int K, N, lt;
        if      (bid2 < 32)  { src = outW;  dst = outT;  K = 128; N = 256; lt = bid2; }
        else if (bid2 < 64)  { src = bandW; dst = bandT; K = 128; N = 256; lt = bid2 - 32; }
        else if (bid2 < 192) { src = modW;  dst = modT;  K = 512; N = 256; lt = bid2 - 64; }
        else                 { src = hvW;   dst = hvT;   K = 256; N = 256; lt = bid2 - 192; }
        int tk = K >> 5;
        int ktile = lt % tk, nt = lt / tk;
        int k0 = ktile * 32, n0 = nt * 32;
        int tx = t & 31, ty = t >> 5;       // 32 x 8
        #pragma unroll
        for (int r = 0; r < 4; r++)
            sm.tr.tile[ty + 8 * r][tx] = src[(size_t)(k0 + ty + 8 * r) * N + n0 + tx];
        __syncthreads();
        #pragma unroll
        for (int r = 0; r < 4; r++)
            dst[(size_t)(n0 + ty + 8 * r) * K + k0 + tx] = f2bf(sm.tr.tile[tx][ty + 8 * r]);
    }
}

// ---------------------------------------------------------------------------
// Launch 2: fused attention + MLP. 512 blocks x 1024 threads (16 waves),
// 2 blocks/CU (32 waves/CU). 16 queries/block. Attention = round-6 coalesced
// structure (wave = query, lane = key / col-pair); o kept in LDS bf16;
// gamma computed in-kernel; MFMA MLP with 16 waves x 16 cols.
// ---------------------------------------------------------------------------
__global__ __launch_bounds__(1024, 8) void fused_kernel(
    const float* __restrict__ x,
    const float* __restrict__ kt, const float* __restrict__ vf,
    const float* __restrict__ qall,
    const unsigned short* __restrict__ outT, const float* __restrict__ out_b,
    const unsigned short* __restrict__ bandT, const float* __restrict__ band_b,
    const unsigned short* __restrict__ modT, const float* __restrict__ mod_b,
    const unsigned short* __restrict__ hvT, const float* __restrict__ hv_b,
    const float* __restrict__ outl_W, const float* __restrict__ outl_b,
    const int* __restrict__ gDp, const int* __restrict__ gHp,
    const int* __restrict__ gWp, const int* __restrict__ gTp,
    float* __restrict__ out)
{
    const int r0 = blockIdx.x * 16;        // global rows (b*QN + q)
    const int b  = r0 >> 12;
    const int q0 = r0 & (QN - 1);
    const int t  = threadIdx.x;
    const int wid = t >> 6, lane = t & 63;
    const int quad = lane >> 4, l16 = lane & 15;

    __shared__ __align__(16) float q_s[16 * 128];
    __shared__ __align__(16) float attn_T[16][256];
    __shared__ __align__(16) unsigned short o_lds[16 * 136];
    __shared__ __align__(16) unsigned short gam_lds[32 * 72];
    __shared__ __align__(16) unsigned short modu_lds[16 * 264];
    __shared__ __align__(16) unsigned short s01_lds[16 * 264];
    __shared__ float sh_xc[64];
    __shared__ int   sh_s[16];
    __shared__ float fin[256];

    // ---- stage q rows, grid coords, window starts ----
    *(float2*)&q_s[t * 2] = *(const float2*)&qall[(size_t)q0 * 128 + t * 2];
    if (t < 64) sh_xc[t] = x[q0 * 4 + t];
    if (t < 16) {
        int gD = gDp[0], gH = gHp[0], gW = gWp[0], gT = gTp[0];
        float g0 = x[(q0 + t) * 4 + 0], g1 = x[(q0 + t) * 4 + 1];
        float g2 = x[(q0 + t) * 4 + 2], g3 = x[(q0 + t) * 4 + 3];
        int zi = (int)(g0 * (float)gD);
        int yi = (int)(g1 * (float)gH);
        int xi = (int)(g2 * (float)gW);
        int ti = (int)(g3 * (float)gT);
        int idx = ((ti * gD + zi) * gH + yi) * gW + xi;
        int Ng = gD * gH * gW * gT;
        float tt = (float)idx / (float)Ng;
        int s = (int)ceilf(tt * (float)LN - ((float)(TOPKN / 2) + 0.5f));
        sh_s[t] = min(max(s, 0), LN - TOPKN);
    }
    __syncthreads();

    // ---- layer gammas: 2 elements per thread ----
    #pragma unroll
    for (int j = 0; j < 2; j++) {
        int e = t * 2 + j;
        int l = e >> 10, g = (e >> 6) & 15, f = e & 63;
        int c = f >> 4, jj = f & 15, oi = jj & 7;
        float om = (float)(10.0 * exp((double)oi * (l ? K_OM1 : K_OM0)));
        float arg = PI_F * sh_xc[g * 4 + c] * om;
        gam_lds[(l * 16 + g) * 72 + f] = f2bf((jj < 8) ? sinf(arg) : cosf(arg));
    }

    // ---- sim + softmax: wave = query g, lane = key; both heads ----
    {
        int g = wid;
        int s = sh_s[g];
        #pragma unroll
        for (int h = 0; h < 2; h++) {
            const float* ktp = kt + (size_t)(b * 128 + h * 64) * LN + s + lane;
            const float* qrow = q_s + g * 128 + h * 64;
            float a0 = 0.f, a1 = 0.f;
            #pragma unroll 8
            for (int d = 0; d < 64; d++) {
                float qd = qrow[d];
                a0 += qd * ktp[(size_t)d * LN];        // keys s+lane
                a1 += qd * ktp[(size_t)d * LN + 64];   // keys s+64+lane
            }
            a0 *= 0.125f; a1 *= 0.125f;
            float m = fmaxf(a0, a1);
            #pragma unroll
            for (int off = 1; off < 64; off <<= 1) m = fmaxf(m, __shfl_xor(m, off));
            float e0 = expf(a0 - m), e1 = expf(a1 - m);
            float ss = e0 + e1;
            #pragma unroll
            for (int off = 1; off < 64; off <<= 1) ss += __shfl_xor(ss, off);
            float inv = 1.f / ss;
            attn_T[g][h * 128 + lane]      = e0 * inv;
            attn_T[g][h * 128 + 64 + lane] = e1 * inv;
        }
    }
    __syncthreads();

    // ---- o = attn @ V : wave = query, lane = col pair -> o_lds bf16 ----
    {
        int g = wid;
        int s = sh_s[g];
        const float* vp = vf + (size_t)(b * LN + s) * 128 + 2 * lane;
        const float* ap = attn_T[g] + (lane >> 5) * 128;
        float oa0 = 0.f, oa1 = 0.f;
        #pragma unroll 8
        for (int k = 0; k < 128; k++) {
            float2 v2 = *(const float2*)(vp + (size_t)k * 128);
            float aw = ap[k];
            oa0 += aw * v2.x; oa1 += aw * v2.y;
        }
        unsigned int packed = (unsigned int)f2bf(oa0) | ((unsigned int)f2bf(oa1) << 16);
        *(unsigned int*)&o_lds[g * 136 + 2 * lane] = packed;
    }
    __syncthreads();

    // ================= MFMA MLP: 16 waves x 16 cols =================
    const int n0 = wid * 16;
    float m0f[4];

    // ---- modulation = o @ out_W + out_b (K=128) ----
    {
        f32x4 acc = (f32x4){0.f, 0.f, 0.f, 0.f};
        #pragma unroll
        for (int kc = 0; kc < 4; kc++) {
            s16x8 a = *(const s16x8*)&o_lds[l16 * 136 + kc * 32 + quad * 8];
            s16x8 bfr = *(const s16x8*)&outT[(size_t)(n0 + l16) * 128 + kc * 32 + quad * 8];
            acc = __builtin_amdgcn_mfma_f32_16x16x32_bf16(a, bfr, acc, 0, 0, 0);
        }
        int col = n0 + l16;
        float bias = out_b[col];
        #pragma unroll
        for (int r = 0; r < 4; r++)
            modu_lds[(quad * 4 + r) * 264 + col] = f2bf(acc[r] + bias);
    }
    __syncthreads();

    // ---- band + mod layers ----
    #pragma unroll
    for (int l = 0; l < 2; l++) {
        f32x4 acc1 = (f32x4){0.f, 0.f, 0.f, 0.f};
        f32x4 acc2 = (f32x4){0.f, 0.f, 0.f, 0.f};
        #pragma unroll
        for (int kc = 0; kc < 2; kc++) {
            s16x8 a = *(const s16x8*)&gam_lds[(l * 16 + l16) * 72 + kc * 32 + quad * 8];
            s16x8 bfr = *(const s16x8*)&bandT[(size_t)(n0 + l16) * 128 + l * 64 + kc * 32 + quad * 8];
            acc1 = __builtin_amdgcn_mfma_f32_16x16x32_bf16(a, bfr, acc1, 0, 0, 0);
        }
        #pragma unroll
        for (int kc = 0; kc < 8; kc++) {
            s16x8 a = *(const s16x8*)&modu_lds[l16 * 264 + kc * 32 + quad * 8];
            s16x8 bfr = *(const s16x8*)&modT[(size_t)(n0 + l16) * 512 + l * 256 + kc * 32 + quad * 8];
            acc2 = __builtin_amdgcn_mfma_f32_16x16x32_bf16(a, bfr, acc2, 0, 0, 0);
        }
        int col = n0 + l16;
        float bb = band_b[l * 256 + col];
        float mb = mod_b[l * 256 + col];
        #pragma unroll
        for (int r = 0; r < 4; r++) {
            float hval = fmaxf(acc1[r] + bb, 0.f);
            float mval = fmaxf(hval + acc2[r] + mb, 0.f);
            if (l == 0) m0f[r] = mval;
            else s01_lds[(quad * 4 + r) * 264 + col] = f2bf(m0f[r] + mval);
        }
    }
    __syncthreads();

    // ---- h_v1 = relu(s01 @ hv_W + hv_b) + scalar head ----
    {
        f32x4 acc = (f32x4){0.f, 0.f, 0.f, 0.f};
        #pragma unroll
        for (int kc = 0; kc < 8; kc++) {
            s16x8 a = *(const s16x8*)&s01_lds[l16 * 264 + kc * 32 + quad * 8];
            s16x8 bfr = *(const s16x8*)&hvT[(size_t)(n0 + l16) * 256 + kc * 32 + quad * 8];
            acc = __builtin_amdgcn_mfma_f32_16x16x32_bf16(a, bfr, acc, 0, 0, 0);
        }
        int col = n0 + l16;
        float w0 = outl_W[col], w1 = outl_W[256 + col], hb = hv_b[col];
        #pragma unroll
        for (int r = 0; r < 4; r++) {
            float hvv = fmaxf(acc[r] + hb, 0.f);
            float pv = m0f[r] * w0 + hvv * w1;
            #pragma unroll
            for (int off = 1; off < 16; off <<= 1) pv += __shfl_xor(pv, off);
            if (l16 == 0) fin[wid * 16 + quad * 4 + r] = pv;
        }
    }
    __syncthreads();
    if (t < 16) {
        float s2 = outl_b[0] + outl_b[1];
        #pragma unroll
        for (int w = 0; w < 16; w++) s2 += fin[w * 16 + t];
        out[r0 + t] = s2;
    }
}

// ---------------------------------------------------------------------------
extern "C" void kernel_launch(void* const* d_in, const int* in_sizes, int n_in,
                              void* d_out, int out_size, void* d_ws, size_t ws_size,
                              hipStream_t stream)
{
    const float* x       = (const float*)d_in[0];
    const float* tokens  = (const float*)d_in[1];
    const float* query_W = (const float*)d_in[2];
    const float* query_b = (const float*)d_in[3];
    const float* q_W     = (const float*)d_in[4];
    const float* kv_W    = (const float*)d_in[5];
    const float* out_W   = (const float*)d_in[6];
    const float* out_b   = (const float*)d_in[7];
    const float* band_W  = (const float*)d_in[8];
    const float* band_b  = (const float*)d_in[9];
    const float* mod_W   = (const float*)d_in[10];
    const float* mod_b   = (const float*)d_in[11];
    const float* hv_W    = (const float*)d_in[12];
    const float* hv_b    = (const float*)d_in[13];
    const float* outl_W  = (const float*)d_in[14];
    const float* outl_b  = (const float*)d_in[15];
    const int*   gD      = (const int*)d_in[16];
    const int*   gH      = (const int*)d_in[17];
    const int*   gW      = (const int*)d_in[18];
    const int*   gT      = (const int*)d_in[19];

    float* ws   = (float*)d_ws;
    float* kt   = ws;                          // 2*128*1024 = 262144 floats
    float* vf   = ws + 262144;                 // 2*1024*128 = 262144 floats
    float* qall = ws + 524288;                 // 4096*128   = 524288 floats
    unsigned short* wb = (unsigned short*)(ws + 1048576);
    unsigned short* outT  = wb;                // 32768 shorts
    unsigned short* bandT = wb + 32768;        // 32768
    unsigned short* modT  = wb + 65536;        // 131072
    unsigned short* hvT   = wb + 196608;       // 65536
    float* out = (float*)d_out;

    prep_kernel<<<512, 256, 0, stream>>>(tokens, kv_W, x, query_W, query_b, q_W,
                                         out_W, band_W, mod_W, hv_W,
                                         kt, vf, qall, outT, bandT, modT, hvT);
    fused_kernel<<<512, 1024, 0, stream>>>(x, kt, vf, qall,
        outT, out_b, bandT, band_b, modT, mod_b, hvT, hv_b,
        outl_W, outl_b, gD, gH, gW, gT, out);
}

// Round 8
// 146.268 us; speedup vs baseline: 2.3237x; 1.2882x over previous
//
#include <hip/hip_runtime.h>
#include <math.h>

// Problem constants (match reference setup_inputs)
#define BN     2
#define QN     4096
#define LN     1024
#define TOPKN  128
#define PI_F   3.14159265358979323846f

// ln(12.8)/7 and ln(3.2)/7 — omegas = 10*exp(i*K), matches jnp.logspace to ~1e-7 rel
#define K_OM0  0.3642064529893673
#define K_OM1  0.1661644014008115

// union-window capacity (keys) and padded pitch for score/P buffers
#define NCMAX  320
#define PFP    328

typedef __attribute__((ext_vector_type(8))) short  s16x8;
typedef __attribute__((ext_vector_type(4))) float  f32x4;

__device__ __forceinline__ unsigned short f2bf(float f) {
    unsigned int u = __float_as_uint(f);
    u = (u + 0x7FFFu + ((u >> 16) & 1u)) >> 16;   // RNE
    return (unsigned short)u;
}

// ---------------------------------------------------------------------------
// Launch 1: prep. blockIdx dispatch:
//   [0,128)   kv path: K -> kbf[b][l][128] bf16 row-major; V -> vtbf[b][j][L] bf16.
//   [128,256) q path: gamma -> xq -> q (fp32 qall), weights self-staged.
//   [256,512) transpose out/band/mod/hv to bf16 wT[n][k].
//   512       counting sort of queries by window start s -> perm, ssort.
// ---------------------------------------------------------------------------
struct KvSmem {
    unsigned short tok_bf[16 * 264];
    unsigned short stage[256 * 40];
    float ktile[128][20];
};
struct QSmem {
    float sh_x[128];
    unsigned short gam_bf[32 * 72];
    unsigned short xq_bf[32 * 264];
    unsigned short stage[256 * 40];
};
struct TrSmem { float tile[32][33]; };
struct SortSmem { int hist[1024]; int psum[256]; };
union PrepSmem { KvSmem kv; QSmem q; TrSmem tr; SortSmem so; };

__global__ __launch_bounds__(256) void prep_kernel(
    const float* __restrict__ tokens, const float* __restrict__ kv_W,
    const float* __restrict__ x, const float* __restrict__ query_W,
    const float* __restrict__ query_b, const float* __restrict__ q_W,
    const float* __restrict__ outW, const float* __restrict__ bandW,
    const float* __restrict__ modW, const float* __restrict__ hvW,
    const int* __restrict__ gDp, const int* __restrict__ gHp,
    const int* __restrict__ gWp, const int* __restrict__ gTp,
    float* __restrict__ qall, unsigned short* __restrict__ kbf,
    unsigned short* __restrict__ vtbf,
    unsigned short* __restrict__ outT, unsigned short* __restrict__ bandT,
    unsigned short* __restrict__ modT, unsigned short* __restrict__ hvT,
    int* __restrict__ perm, int* __restrict__ ssort)
{
    __shared__ __align__(16) PrepSmem sm;
    const int bid = blockIdx.x, t = threadIdx.x;

    if (bid < 128) {
        // ------------------------- kv path -------------------------
        int l0 = bid * 16;
        int b = l0 >> 10, lloc = l0 & 1023;
        #pragma unroll
        for (int i = 0; i < 16; i++)
            sm.kv.tok_bf[i * 264 + t] = f2bf(tokens[(size_t)(l0 + i) * 256 + t]);
        int w = t >> 6, lane = t & 63, quad = lane >> 4, l16 = lane & 15;
        int n0 = w * 64;
        f32x4 acc[4];
        #pragma unroll
        for (int s = 0; s < 4; s++) acc[s] = (f32x4){0.f, 0.f, 0.f, 0.f};
        for (int kc = 0; kc < 8; kc++) {
            __syncthreads();
            #pragma unroll
            for (int i = 0; i < 32; i++)
                sm.kv.stage[t * 40 + i] = f2bf(kv_W[(size_t)(kc * 32 + i) * 256 + t]);
            __syncthreads();
            s16x8 a = *(const s16x8*)&sm.kv.tok_bf[l16 * 264 + kc * 32 + quad * 8];
            #pragma unroll
            for (int sub = 0; sub < 4; sub++) {
                s16x8 bfr = *(const s16x8*)&sm.kv.stage[(n0 + sub * 16 + l16) * 40 + quad * 8];
                acc[sub] = __builtin_amdgcn_mfma_f32_16x16x32_bf16(a, bfr, acc[sub], 0, 0, 0);
            }
        }
        if (w < 2) {       // K half -> kbf row-major bf16
            #pragma unroll
            for (int sub = 0; sub < 4; sub++)
                #pragma unroll
                for (int r = 0; r < 4; r++)
                    kbf[(size_t)(l0 + quad * 4 + r) * 128 + n0 + sub * 16 + l16] =
                        f2bf(acc[sub][r]);
        } else {           // V half -> LDS tile for transpose
            #pragma unroll
            for (int sub = 0; sub < 4; sub++)
                #pragma unroll
                for (int r = 0; r < 4; r++)
                    sm.kv.ktile[(n0 - 128) + sub * 16 + l16][quad * 4 + r] = acc[sub][r];
        }
        __syncthreads();
        {   // write vtbf: thread pair per V-col, 8 keys each (16B store)
            int col = t >> 1, half = t & 1;
            s16x8 pk;
            #pragma unroll
            for (int j = 0; j < 8; j++)
                pk[j] = (short)f2bf(sm.kv.ktile[col][half * 8 + j]);
            *(s16x8*)&vtbf[(size_t)(b * 128 + col) * 1024 + lloc + half * 8] = pk;
        }
    } else if (bid < 256) {
        // ------------------------- q path -------------------------
        int p0 = (bid - 128) * 32;
        if (t < 128) sm.q.sh_x[t] = x[p0 * 4 + t];
        __syncthreads();
        {
            int e0 = t * 8;
            int g = e0 >> 6;
            #pragma unroll
            for (int j = 0; j < 8; j++) {
                int f = (e0 + j) & 63;
                int c = f >> 4, jj = f & 15, oi = jj & 7;
                float om = (float)(10.0 * exp((double)oi * K_OM0));
                float arg = PI_F * sm.q.sh_x[g * 4 + c] * om;
                sm.q.gam_bf[g * 72 + f] = f2bf((jj < 8) ? sinf(arg) : cosf(arg));
            }
        }
        int w = t >> 6, lane = t & 63, quad = lane >> 4, l16 = lane & 15;
        int m0 = (w >> 1) * 16;
        {
            int n0a = (w & 1) * 128;
            f32x4 acc[8];
            #pragma unroll
            for (int s = 0; s < 8; s++) acc[s] = (f32x4){0.f, 0.f, 0.f, 0.f};
            for (int kc = 0; kc < 2; kc++) {
                __syncthreads();
                #pragma unroll
                for (int i = 0; i < 32; i++)
                    sm.q.stage[t * 40 + i] = f2bf(query_W[(size_t)(kc * 32 + i) * 256 + t]);
                __syncthreads();
                s16x8 a = *(const s16x8*)&sm.q.gam_bf[(m0 + l16) * 72 + kc * 32 + quad * 8];
                #pragma unroll
                for (int sub = 0; sub < 8; sub++) {
                    s16x8 bfr = *(const s16x8*)&sm.q.stage[(n0a + sub * 16 + l16) * 40 + quad * 8];
                    acc[sub] = __builtin_amdgcn_mfma_f32_16x16x32_bf16(a, bfr, acc[sub], 0, 0, 0);
                }
            }
            #pragma unroll
            for (int sub = 0; sub < 8; sub++) {
                int col = n0a + sub * 16 + l16;
                float bias = query_b[col];
                #pragma unroll
                for (int r = 0; r < 4; r++)
                    sm.q.xq_bf[(m0 + quad * 4 + r) * 264 + col] = f2bf(fmaxf(acc[sub][r] + bias, 0.f));
            }
        }
        {
            int n0b = (w & 1) * 64;
            f32x4 acc2[4];
            #pragma unroll
            for (int s = 0; s < 4; s++) acc2[s] = (f32x4){0.f, 0.f, 0.f, 0.f};
            for (int kc = 0; kc < 8; kc++) {
                __syncthreads();
                #pragma unroll
                for (int i = 0; i < 16; i++) {
                    int e = i * 256 + t;
                    int k = e >> 7, n = e & 127;
                    sm.q.stage[n * 40 + k] = f2bf(q_W[(size_t)(kc * 32 + k) * 128 + n]);
                }
                __syncthreads();
                s16x8 a = *(const s16x8*)&sm.q.xq_bf[(m0 + l16) * 264 + kc * 32 + quad * 8];
                #pragma unroll
                for (int sub = 0; sub < 4; sub++) {
                    s16x8 bfr = *(const s16x8*)&sm.q.stage[(n0b + sub * 16 + l16) * 40 + quad * 8];
                    acc2[sub] = __builtin_amdgcn_mfma_f32_16x16x32_bf16(a, bfr, acc2[sub], 0, 0, 0);
                }
            }
            #pragma unroll
            for (int sub = 0; sub < 4; sub++)
                #pragma unroll
                for (int r = 0; r < 4; r++)
                    qall[(size_t)(p0 + m0 + quad * 4 + r) * 128 + n0b + sub * 16 + l16] = acc2[sub][r];
        }
    } else if (bid < 512) {
        // --------------------- transpose path ---------------------
        int bid2 = bid - 256;
        const float* src; unsigned short* dst; int K, N, lt;
        if      (bid2 < 32)  { src = outW;  dst = outT;  K = 128; N = 256; lt = bid2; }
        else if (bid2 < 64)  { src = bandW; dst = bandT; K = 128; N = 256; lt = bid2 - 32; }
        else if (bid2 < 192) { src = modW;  dst = modT;  K = 512; N = 256; lt = bid2 - 64; }
        else                 { src = hvW;   dst = hvT;   K = 256; N = 256; lt = bid2 - 192; }
        int tk = K >> 5;
        int ktile = lt % tk, nt = lt / tk;
        int k0 = ktile * 32, n0 = nt * 32;
        int tx = t & 31, ty = t >> 5;
        #pragma unroll
        for (int r = 0; r < 4; r++)
            sm.tr.tile[ty + 8 * r][tx] = src[(size_t)(k0 + ty + 8 * r) * N + n0 + tx];
        __syncthreads();
        #pragma unroll
        for (int r = 0; r < 4; r++)
            dst[(size_t)(n0 + ty + 8 * r) * K + k0 + tx] = f2bf(sm.tr.tile[tx][ty + 8 * r]);
    } else {
        // ------------------- sort path (1 block) -------------------
        int gD = gDp[0], gH = gHp[0], gW = gWp[0], gT = gTp[0];
        int Ng = gD * gH * gW * gT;
        #pragma unroll
        for (int i = 0; i < 4; i++) sm.so.hist[t + 256 * i] = 0;
        __syncthreads();
        int sarr[16];
        #pragma unroll
        for (int i = 0; i < 16; i++) {
            int q = i * 256 + t;
            float4 xv = *(const float4*)&x[q * 4];
            int zi = (int)(xv.x * (float)gD);
            int yi = (int)(xv.y * (float)gH);
            int xi = (int)(xv.z * (float)gW);
            int ti = (int)(xv.w * (float)gT);
            int idx = ((ti * gD + zi) * gH + yi) * gW + xi;
            float tt = (float)idx / (float)Ng;
            int s = (int)ceilf(tt * (float)LN - ((float)(TOPKN / 2) + 0.5f));
            s = min(max(s, 0), LN - TOPKN);
            sarr[i] = s;
            atomicAdd(&sm.so.hist[s], 1);
        }
        __syncthreads();
        int sum4 = sm.so.hist[4 * t] + sm.so.hist[4 * t + 1]
                 + sm.so.hist[4 * t + 2] + sm.so.hist[4 * t + 3];
        sm.so.psum[t] = sum4;
        __syncthreads();
        for (int off = 1; off < 256; off <<= 1) {
            int v = (t >= off) ? sm.so.psum[t - off] : 0;
            __syncthreads();
            sm.so.psum[t] += v;
            __syncthreads();
        }
        int base = sm.so.psum[t] - sum4;
        int b0 = sm.so.hist[4 * t], b1 = sm.so.hist[4 * t + 1], b2 = sm.so.hist[4 * t + 2];
        sm.so.hist[4 * t] = base;
        sm.so.hist[4 * t + 1] = base + b0;
        sm.so.hist[4 * t + 2] = base + b0 + b1;
        sm.so.hist[4 * t + 3] = base + b0 + b1 + b2;
        __syncthreads();
        #pragma unroll
        for (int i = 0; i < 16; i++) {
            int q = i * 256 + t;
            int pos = atomicAdd(&sm.so.hist[sarr[i]], 1);
            perm[pos] = q;
            ssort[pos] = sarr[i];
        }
    }
}

// ---------------------------------------------------------------------------
// Launch 2: fused. 512 blocks x 1024 threads, 2 blocks/CU. 16 SORTED queries
// per block; attention = dense MFMA GEMMs over the union window with per-query
// masking; MLP = round-7 verified MFMA chain; final scalars scattered by perm.
// ---------------------------------------------------------------------------
__global__ __launch_bounds__(1024, 8) void fused_kernel(
    const float* __restrict__ x,
    const unsigned short* __restrict__ kbf, const unsigned short* __restrict__ vtbf,
    const float* __restrict__ qall,
    const int* __restrict__ perm, const int* __restrict__ ssort,
    const unsigned short* __restrict__ outT, const float* __restrict__ out_b,
    const unsigned short* __restrict__ bandT, const float* __restrict__ band_b,
    const unsigned short* __restrict__ modT, const float* __restrict__ mod_b,
    const unsigned short* __restrict__ hvT, const float* __restrict__ hv_b,
    const float* __restrict__ outl_W, const float* __restrict__ outl_b,
    float* __restrict__ out)
{
    const int bid = blockIdx.x;
    const int b   = bid >> 8;
    const int sp0 = (bid & 255) * 16;
    const int t   = threadIdx.x;
    const int wid = t >> 6, lane = t & 63;
    const int quad = lane >> 4, l16 = lane & 15;

    __shared__ __align__(16) unsigned short q_bf[16 * 136];
    __shared__ __align__(16) unsigned short gam_lds[32 * 72];
    __shared__ __align__(16) unsigned short P_bf[32 * PFP];
    __shared__ __align__(16) unsigned char regionA[PFP * 16 * 4];   // scores / o_part / modu+s01
    __shared__ __align__(16) unsigned short o_lds[16 * 136];
    __shared__ float fin[256];
    __shared__ float sh_xc[64];
    __shared__ int sh_pq[16], sh_s[16];

    float* P_f32 = (float*)regionA;
    float* o_part = (float*)regionA;
    unsigned short* modu_lds = (unsigned short*)regionA;
    unsigned short* s01_lds  = (unsigned short*)(regionA + 16 * 264 * 2);

    if (t < 16) { sh_pq[t] = perm[sp0 + t]; sh_s[t] = ssort[sp0 + t]; }
    __syncthreads();

    // ---- stage q (bf16 A-rows) and grid coords ----
    {
        int m = t >> 6, d = (t & 63) * 2;
        float2 qv = *(const float2*)&qall[(size_t)sh_pq[m] * 128 + d];
        unsigned int pk = (unsigned int)f2bf(qv.x) | ((unsigned int)f2bf(qv.y) << 16);
        *(unsigned int*)&q_bf[m * 136 + d] = pk;
    }
    if (t < 64) sh_xc[t] = x[(size_t)sh_pq[t >> 2] * 4 + (t & 3)];
    __syncthreads();

    // ---- layer gammas (sorted order) ----
    #pragma unroll
    for (int j = 0; j < 2; j++) {
        int e = t * 2 + j;
        int l = e >> 10, g = (e >> 6) & 15, f = e & 63;
        int c = f >> 4, jj = f & 15, oi = jj & 7;
        float om = (float)(10.0 * exp((double)oi * (l ? K_OM1 : K_OM0)));
        float arg = PI_F * sh_xc[g * 4 + c] * om;
        gam_lds[(l * 16 + g) * 72 + f] = f2bf((jj < 8) ? sinf(arg) : cosf(arg));
    }

    const int u0    = sh_s[0] & ~7;
    const int ncols = min((sh_s[15] + 128 - u0 + 31) & ~31, NCMAX);
    const int nsub  = ncols >> 4;
    const int nkc   = ncols >> 5;

    // ---- attention: heads sequential (scores MFMA -> masked softmax) ----
    #pragma unroll
    for (int h = 0; h < 2; h++) {
        s16x8 aq0 = *(const s16x8*)&q_bf[l16 * 136 + h * 64 + quad * 8];
        s16x8 aq1 = *(const s16x8*)&q_bf[l16 * 136 + h * 64 + 32 + quad * 8];
        for (int sub = wid; sub < nsub; sub += 16) {
            f32x4 acc = (f32x4){0.f, 0.f, 0.f, 0.f};
            size_t krow = (size_t)(b * 1024 + u0 + sub * 16 + l16) * 128 + h * 64 + quad * 8;
            s16x8 b0 = *(const s16x8*)&kbf[krow];
            s16x8 b1 = *(const s16x8*)&kbf[krow + 32];
            acc = __builtin_amdgcn_mfma_f32_16x16x32_bf16(aq0, b0, acc, 0, 0, 0);
            acc = __builtin_amdgcn_mfma_f32_16x16x32_bf16(aq1, b1, acc, 0, 0, 0);
            #pragma unroll
            for (int r = 0; r < 4; r++)
                P_f32[(quad * 4 + r) * PFP + sub * 16 + l16] = acc[r];
        }
        __syncthreads();
        // masked softmax: wave = sorted query g
        {
            int g = wid;
            int sg = sh_s[g];
            float vals[5]; int ok[5];
            float mx = -1e30f;
            #pragma unroll
            for (int i = 0; i < 5; i++) {
                int c = lane + 64 * i;
                float v = P_f32[g * PFP + c] * 0.125f;
                int key = u0 + c;
                int o2 = (c < ncols) && (key >= sg) && (key < sg + 128);
                vals[i] = v; ok[i] = o2;
                if (o2) mx = fmaxf(mx, v);
            }
            #pragma unroll
            for (int off = 1; off < 64; off <<= 1) mx = fmaxf(mx, __shfl_xor(mx, off));
            float sum = 0.f, e5[5];
            #pragma unroll
            for (int i = 0; i < 5; i++) {
                float e = ok[i] ? expf(vals[i] - mx) : 0.f;
                e5[i] = e; sum += e;
            }
            #pragma unroll
            for (int off = 1; off < 64; off <<= 1) sum += __shfl_xor(sum, off);
            float inv = 1.f / sum;
            #pragma unroll
            for (int i = 0; i < 5; i++) {
                int c = lane + 64 * i;
                if (c < ncols) P_bf[(h * 16 + g) * PFP + c] = f2bf(e5[i] * inv);
            }
        }
        __syncthreads();
    }

    // ---- P @ V (MFMA): wave = (col-subtile, K-half) ----
    {
        int n0 = (wid & 7) * 16;
        int hh = n0 >> 6;
        int khalf = wid >> 3;
        int nk2 = (nkc + 1) >> 1;
        int k0 = khalf ? nk2 : 0;
        int k1 = khalf ? nkc : nk2;
        f32x4 acc = (f32x4){0.f, 0.f, 0.f, 0.f};
        for (int kc = k0; kc < k1; kc++) {
            s16x8 a = *(const s16x8*)&P_bf[(hh * 16 + l16) * PFP + kc * 32 + quad * 8];
            int koff = u0 + kc * 32 + quad * 8;
            koff = min(koff, 1016);   // clamp pure-garbage chunks (P=0 there)
            s16x8 bfr = *(const s16x8*)&vtbf[(size_t)(b * 128 + n0 + l16) * 1024 + koff];
            acc = __builtin_amdgcn_mfma_f32_16x16x32_bf16(a, bfr, acc, 0, 0, 0);
        }
        #pragma unroll
        for (int r = 0; r < 4; r++)
            o_part[(khalf * 16 + quad * 4 + r) * 128 + n0 + l16] = acc[r];
    }
    __syncthreads();

    // ---- o assembly: combine K-halves -> o_lds bf16 ----
    {
        int m = t >> 6, j2 = (t & 63) * 2;
        float v0 = o_part[m * 128 + j2]     + o_part[(16 + m) * 128 + j2];
        float v1 = o_part[m * 128 + j2 + 1] + o_part[(16 + m) * 128 + j2 + 1];
        unsigned int pk = (unsigned int)f2bf(v0) | ((unsigned int)f2bf(v1) << 16);
        *(unsigned int*)&o_lds[m * 136 + j2] = pk;
    }
    __syncthreads();

    // ================= MFMA MLP (round-7 verified) =================
    const int n0 = wid * 16;
    float m0f[4];

    {   // modulation = o @ out_W + out_b (K=128)
        f32x4 acc = (f32x4){0.f, 0.f, 0.f, 0.f};
        #pragma unroll
        for (int kc = 0; kc < 4; kc++) {
            s16x8 a = *(const s16x8*)&o_lds[l16 * 136 + kc * 32 + quad * 8];
            s16x8 bfr = *(const s16x8*)&outT[(size_t)(n0 + l16) * 128 + kc * 32 + quad * 8];
            acc = __builtin_amdgcn_mfma_f32_16x16x32_bf16(a, bfr, acc, 0, 0, 0);
        }
        int col = n0 + l16;
        float bias = out_b[col];
        #pragma unroll
        for (int r = 0; r < 4; r++)
            modu_lds[(quad * 4 + r) * 264 + col] = f2bf(acc[r] + bias);
    }
    __syncthreads();

    #pragma unroll
    for (int l = 0; l < 2; l++) {
        f32x4 acc1 = (f32x4){0.f, 0.f, 0.f, 0.f};
        f32x4 acc2 = (f32x4){0.f, 0.f, 0.f, 0.f};
        #pragma unroll
        for (int kc = 0; kc < 2; kc++) {
            s16x8 a = *(const s16x8*)&gam_lds[(l * 16 + l16) * 72 + kc * 32 + quad * 8];
            s16x8 bfr = *(const s16x8*)&bandT[(size_t)(n0 + l16) * 128 + l * 64 + kc * 32 + quad * 8];
            acc1 = __builtin_amdgcn_mfma_f32_16x16x32_bf16(a, bfr, acc1, 0, 0, 0);
        }
        #pragma unroll
        for (int kc = 0; kc < 8; kc++) {
            s16x8 a = *(const s16x8*)&modu_lds[l16 * 264 + kc * 32 + quad * 8];
            s16x8 bfr = *(const s16x8*)&modT[(size_t)(n0 + l16) * 512 + l * 256 + kc * 32 + quad * 8];
            acc2 = __builtin_amdgcn_mfma_f32_16x16x32_bf16(a, bfr, acc2, 0, 0, 0);
        }
        int col = n0 + l16;
        float bb = band_b[l * 256 + col];
        float mb = mod_b[l * 256 + col];
        #pragma unroll
        for (int r = 0; r < 4; r++) {
            float hval = fmaxf(acc1[r] + bb, 0.f);
            float mval = fmaxf(hval + acc2[r] + mb, 0.f);
            if (l == 0) m0f[r] = mval;
            else s01_lds[(quad * 4 + r) * 264 + col] = f2bf(m0f[r] + mval);
        }
    }
    __syncthreads();

    {   // h_v1 = relu(s01 @ hv_W + hv_b) + scalar head
        f32x4 acc = (f32x4){0.f, 0.f, 0.f, 0.f};
        #pragma unroll
        for (int kc = 0; kc < 8; kc++) {
            s16x8 a = *(const s16x8*)&s01_lds[l16 * 264 + kc * 32 + quad * 8];
            s16x8 bfr = *(const s16x8*)&hvT[(size_t)(n0 + l16) * 256 + kc * 32 + quad * 8];
            acc = __builtin_amdgcn_mfma_f32_16x16x32_bf16(a, bfr, acc, 0, 0, 0);
        }
        int col = n0 + l16;
        float w0 = outl_W[col], w1 = outl_W[256 + col], hb = hv_b[col];
        #pragma unroll
        for (int r = 0; r < 4; r++) {
            float hvv = fmaxf(acc[r] + hb, 0.f);
            float pv = m0f[r] * w0 + hvv * w1;
            #pragma unroll
            for (int off = 1; off < 16; off <<= 1) pv += __shfl_xor(pv, off);
            if (l16 == 0) fin[wid * 16 + quad * 4 + r] = pv;
        }
    }
    __syncthreads();
    if (t < 16) {
        float s2 = outl_b[0] + outl_b[1];
        #pragma unroll
        for (int w = 0; w < 16; w++) s2 += fin[w * 16 + t];
        out[(size_t)b * QN + sh_pq[t]] = s2;   // scatter by permutation
    }
}

// ---------------------------------------------------------------------------
extern "C" void kernel_launch(void* const* d_in, const int* in_sizes, int n_in,
                              void* d_out, int out_size, void* d_ws, size_t ws_size,
                              hipStream_t stream)
{
    const float* x       = (const float*)d_in[0];
    const float* tokens  = (const float*)d_in[1];
    const float* query_W = (const float*)d_in[2];
    const float* query_b = (const float*)d_in[3];
    const float* q_W     = (const float*)d_in[4];
    const float* kv_W    = (const float*)d_in[5];
    const float* out_W   = (const float*)d_in[6];
    const float* out_b   = (const float*)d_in[7];
    const float* band_W  = (const float*)d_in[8];
    const float* band_b  = (const float*)d_in[9];
    const float* mod_W   = (const float*)d_in[10];
    const float* mod_b   = (const float*)d_in[11];
    const float* hv_W    = (const float*)d_in[12];
    const float* hv_b    = (const float*)d_in[13];
    const float* outl_W  = (const float*)d_in[14];
    const float* outl_b  = (const float*)d_in[15];
    const int*   gD      = (const int*)d_in[16];
    const int*   gH      = (const int*)d_in[17];
    const int*   gW      = (const int*)d_in[18];
    const int*   gT      = (const int*)d_in[19];

    float* ws   = (float*)d_ws;
    float* qall = ws;                               // 4096*128 fp32
    unsigned short* wb = (unsigned short*)(ws + 524288);
    unsigned short* kbf   = wb;                     // 2*1024*128 bf16
    unsigned short* vtbf  = wb + 262144;            // 2*128*1024 bf16
    unsigned short* outT  = wb + 524288;            // 32768
    unsigned short* bandT = wb + 557056;            // 32768
    unsigned short* modT  = wb + 589824;            // 131072
    unsigned short* hvT   = wb + 720896;            // 65536
    int* perm  = (int*)(wb + 786432);               // 4096 ints
    int* ssort = perm + 4096;                       // 4096 ints
    float* out = (float*)d_out;

    prep_kernel<<<513, 256, 0, stream>>>(tokens, kv_W, x, query_W, query_b, q_W,
                                         out_W, band_W, mod_W, hv_W,
                                         gD, gH, gW, gT,
                                         qall, kbf, vtbf, outT, bandT, modT, hvT,
                                         perm, ssort);
    fused_kernel<<<512, 1024, 0, stream>>>(x, kbf, vtbf, qall, perm, ssort,
        outT, out_b, bandT, band_b, modT, mod_b, hvT, hv_b,
        outl_W, outl_b, out);
}

// Round 10
// 145.838 us; speedup vs baseline: 2.3306x; 1.0029x over previous
//
#include <hip/hip_runtime.h>
#include <math.h>

// Problem constants (match reference setup_inputs)
#define BN     2
#define QN     4096
#define LN     1024
#define TOPKN  128
#define PI_F   3.14159265358979323846f

// ln(12.8)/7 and ln(3.2)/7 — omegas = 10*exp(i*K), matches jnp.logspace to ~1e-7 rel
#define K_OM0  0.3642064529893673
#define K_OM1  0.1661644014008115

// union-window capacity (keys) and padded pitch for score/P buffers
#define NCMAX  320
#define PFP    328

typedef __attribute__((ext_vector_type(8))) short  s16x8;
typedef __attribute__((ext_vector_type(4))) short  s16x4;
typedef __attribute__((ext_vector_type(4))) float  f32x4;
typedef unsigned short u16;

__device__ __forceinline__ u16 f2bf(float f) {
    unsigned int u = __float_as_uint(f);
    u = (u + 0x7FFFu + ((u >> 16) & 1u)) >> 16;   // RNE
    return (u16)u;
}

// ---------------------------------------------------------------------------
// Launch 1: prep, 449 blocks x 1024 threads. Role dispatch:
//   [0,64)    kv path: 32 token rows/block, kv_W self-staged; K -> kbf bf16
//             row-major, V -> vtbf bf16 transposed.
//   [64,192)  q path: 32 queries/block; gamma -> xq -> q (fp32 qall).
//   [192,448) transpose out/band/mod/hv to bf16 wT[n][k], 1 elem/thread.
//   448       counting sort of queries by window start s -> perm, ssort.
// ---------------------------------------------------------------------------
struct KvS { u16 tok[32 * 264]; u16 stage[256 * 40]; float vtile[128][40]; };
struct QS  { float shx[128]; u16 gam[32 * 72]; u16 xq[32 * 264]; u16 stage[256 * 40]; };
struct TrS { float tile[32][33]; };
struct SoS { int hist[1024]; int cur[1024]; };
union PrepS { KvS kv; QS q; TrS tr; SoS so; };

__global__ __launch_bounds__(1024) void prep_kernel(
    const float* __restrict__ tokens, const float* __restrict__ kv_W,
    const float* __restrict__ x, const float* __restrict__ query_W,
    const float* __restrict__ query_b, const float* __restrict__ q_W,
    const float* __restrict__ outW, const float* __restrict__ bandW,
    const float* __restrict__ modW, const float* __restrict__ hvW,
    const int* __restrict__ gDp, const int* __restrict__ gHp,
    const int* __restrict__ gWp, const int* __restrict__ gTp,
    float* __restrict__ qall, u16* __restrict__ kbf, u16* __restrict__ vtbf,
    u16* __restrict__ outT, u16* __restrict__ bandT,
    u16* __restrict__ modT, u16* __restrict__ hvT,
    int* __restrict__ perm, int* __restrict__ ssort)
{
    __shared__ __align__(16) PrepS sm;
    const int bid = blockIdx.x;
    const int t   = threadIdx.x;
    const int wid = t >> 6, lane = t & 63;
    const int quad = lane >> 4, l16 = lane & 15;

    if (bid < 64) {
        // ---- kv path: 32 token rows/block, 16 waves ----
        int l0 = bid * 32;
        int b = l0 >> 10, lloc = l0 & 1023;
        #pragma unroll
        for (int i = 0; i < 8; i++) {
            int idx = i * 1024 + t; int row = idx >> 8, col = idx & 255;
            sm.kv.tok[row * 264 + col] = f2bf(tokens[(size_t)(l0 + row) * 256 + col]);
        }
        int m0 = (wid & 1) * 16;
        int c0 = (wid >> 1) * 32;
        f32x4 acc[2];
        acc[0] = (f32x4){0.f, 0.f, 0.f, 0.f};
        acc[1] = (f32x4){0.f, 0.f, 0.f, 0.f};
        for (int kc = 0; kc < 8; kc++) {
            __syncthreads();
            #pragma unroll
            for (int i = 0; i < 8; i++) {
                int idx = i * 1024 + t; int k = idx >> 8, n = idx & 255;
                sm.kv.stage[n * 40 + k] = f2bf(kv_W[(size_t)(kc * 32 + k) * 256 + n]);
            }
            __syncthreads();
            s16x8 a = *(const s16x8*)&sm.kv.tok[(m0 + l16) * 264 + kc * 32 + quad * 8];
            #pragma unroll
            for (int sub = 0; sub < 2; sub++) {
                s16x8 bfr = *(const s16x8*)&sm.kv.stage[(c0 + sub * 16 + l16) * 40 + quad * 8];
                acc[sub] = __builtin_amdgcn_mfma_f32_16x16x32_bf16(a, bfr, acc[sub], 0, 0, 0);
            }
        }
        #pragma unroll
        for (int sub = 0; sub < 2; sub++) {
            int col = c0 + sub * 16 + l16;
            if (col < 128) {
                #pragma unroll
                for (int r = 0; r < 4; r++)
                    kbf[(size_t)(l0 + m0 + quad * 4 + r) * 128 + col] = f2bf(acc[sub][r]);
            } else {
                #pragma unroll
                for (int r = 0; r < 4; r++)
                    sm.kv.vtile[col - 128][m0 + quad * 4 + r] = acc[sub][r];
            }
        }
        __syncthreads();
        {   // vtbf: 4 bf16 per thread (8B store), 16B-aligned vtile reads (pitch 40)
            int col = t >> 3, rg = (t & 7) * 4;
            float4 v4 = *(const float4*)&sm.kv.vtile[col][rg];
            s16x4 pk;
            pk[0] = (short)f2bf(v4.x); pk[1] = (short)f2bf(v4.y);
            pk[2] = (short)f2bf(v4.z); pk[3] = (short)f2bf(v4.w);
            *(s16x4*)&vtbf[(size_t)(b * 128 + col) * 1024 + lloc + rg] = pk;
        }
    } else if (bid < 192) {
        // ---- q path: 32 queries/block, 16 waves ----
        int p0 = (bid - 64) * 32;
        if (t < 128) sm.q.shx[t] = x[p0 * 4 + t];
        __syncthreads();
        #pragma unroll
        for (int j = 0; j < 2; j++) {
            int e = t * 2 + j;
            int g = e >> 6, f = e & 63;
            int c = f >> 4, jj = f & 15, oi = jj & 7;
            float om = (float)(10.0 * exp((double)oi * K_OM0));
            float arg = PI_F * sm.q.shx[g * 4 + c] * om;
            sm.q.gam[g * 72 + f] = f2bf((jj < 8) ? sinf(arg) : cosf(arg));
        }
        int m0 = (wid & 1) * 16;
        {   // stage 1: xq = relu(gamma @ query_W + b)
            int c0 = (wid >> 1) * 32;
            f32x4 acc[2];
            acc[0] = (f32x4){0.f, 0.f, 0.f, 0.f};
            acc[1] = (f32x4){0.f, 0.f, 0.f, 0.f};
            for (int kc = 0; kc < 2; kc++) {
                __syncthreads();
                #pragma unroll
                for (int i = 0; i < 8; i++) {
                    int idx = i * 1024 + t; int k = idx >> 8, n = idx & 255;
                    sm.q.stage[n * 40 + k] = f2bf(query_W[(size_t)(kc * 32 + k) * 256 + n]);
                }
                __syncthreads();
                s16x8 a = *(const s16x8*)&sm.q.gam[(m0 + l16) * 72 + kc * 32 + quad * 8];
                #pragma unroll
                for (int sub = 0; sub < 2; sub++) {
                    s16x8 bfr = *(const s16x8*)&sm.q.stage[(c0 + sub * 16 + l16) * 40 + quad * 8];
                    acc[sub] = __builtin_amdgcn_mfma_f32_16x16x32_bf16(a, bfr, acc[sub], 0, 0, 0);
                }
            }
            #pragma unroll
            for (int sub = 0; sub < 2; sub++) {
                int col = c0 + sub * 16 + l16;
                float bias = query_b[col];
                #pragma unroll
                for (int r = 0; r < 4; r++)
                    sm.q.xq[(m0 + quad * 4 + r) * 264 + col] = f2bf(fmaxf(acc[sub][r] + bias, 0.f));
            }
        }
        {   // stage 2: q = xq @ q_W
            int n0q = (wid >> 1) * 16;
            f32x4 acc2 = (f32x4){0.f, 0.f, 0.f, 0.f};
            for (int kc = 0; kc < 8; kc++) {
                __syncthreads();
                #pragma unroll
                for (int i = 0; i < 4; i++) {
                    int idx = i * 1024 + t; int k = idx >> 7, n = idx & 127;
                    sm.q.stage[n * 40 + k] = f2bf(q_W[(size_t)(kc * 32 + k) * 128 + n]);
                }
                __syncthreads();
                s16x8 a = *(const s16x8*)&sm.q.xq[(m0 + l16) * 264 + kc * 32 + quad * 8];
                s16x8 bfr = *(const s16x8*)&sm.q.stage[(n0q + l16) * 40 + quad * 8];
                acc2 = __builtin_amdgcn_mfma_f32_16x16x32_bf16(a, bfr, acc2, 0, 0, 0);
            }
            #pragma unroll
            for (int r = 0; r < 4; r++)
                qall[(size_t)(p0 + m0 + quad * 4 + r) * 128 + n0q + l16] = acc2[r];
        }
    } else if (bid < 448) {
        // ---- transpose path: one 32x32 tile/block, 1 elem/thread ----
        int bid2 = bid - 192;
        const float* src; u16* dst; int K, N, lt;
        if      (bid2 < 32)  { src = outW;  dst = outT;  K = 128; N = 256; lt = bid2; }
        else if (bid2 < 64)  { src = bandW; dst = bandT; K = 128; N = 256; lt = bid2 - 32; }
        else if (bid2 < 192) { src = modW;  dst = modT;  K = 512; N = 256; lt = bid2 - 64; }
        else                 { src = hvW;   dst = hvT;   K = 256; N = 256; lt = bid2 - 192; }
        int tk = K >> 5;
        int ktile = lt % tk, nt = lt / tk;
        int k0 = ktile * 32, n0 = nt * 32;
        int tx = t & 31, ty = (t >> 5) & 31;
        sm.tr.tile[ty][tx] = src[(size_t)(k0 + ty) * N + n0 + tx];
        __syncthreads();
        dst[(size_t)(n0 + ty) * K + k0 + tx] = f2bf(sm.tr.tile[tx][ty]);
    } else {
        // ---- sort path: counting sort by window start, 1024 threads ----
        int gD = gDp[0], gH = gHp[0], gW = gWp[0], gT = gTp[0];
        int Ng = gD * gH * gW * gT;
        sm.so.hist[t] = 0;
        __syncthreads();
        int sarr[4];
        #pragma unroll
        for (int i = 0; i < 4; i++) {
            int q = i * 1024 + t;
            float4 xv = *(const float4*)&x[q * 4];
            int zi = (int)(xv.x * (float)gD);
            int yi = (int)(xv.y * (float)gH);
            int xi = (int)(xv.z * (float)gW);
            int ti = (int)(xv.w * (float)gT);
            int idx = ((ti * gD + zi) * gH + yi) * gW + xi;
            float tt = (float)idx / (float)Ng;
            int s = (int)ceilf(tt * (float)LN - ((float)(TOPKN / 2) + 0.5f));
            s = min(max(s, 0), LN - TOPKN);
            sarr[i] = s;
            atomicAdd(&sm.so.hist[s], 1);
        }
        __syncthreads();
        int cnt = sm.so.hist[t];
        sm.so.cur[t] = cnt;
        __syncthreads();
        for (int off = 1; off < 1024; off <<= 1) {
            int u = (t >= off) ? sm.so.cur[t - off] : 0;
            __syncthreads();
            sm.so.cur[t] += u;
            __syncthreads();
        }
        int excl = sm.so.cur[t] - cnt;
        __syncthreads();
        sm.so.hist[t] = excl;   // reuse hist as placement cursor
        __syncthreads();
        #pragma unroll
        for (int i = 0; i < 4; i++) {
            int q = i * 1024 + t;
            int pos = atomicAdd(&sm.so.hist[sarr[i]], 1);
            perm[pos] = q;
            ssort[pos] = sarr[i];
        }
    }
}

// ---------------------------------------------------------------------------
// Launch 2: fused. 512 blocks x 1024 threads, 2 blocks/CU. 16 SORTED queries
// per block; attention = dense MFMA GEMMs over the union window with per-query
// masking; MLP = verified MFMA chain; final scalars scattered by perm.
// (Round-8 verified body, verbatim.)
// ---------------------------------------------------------------------------
__global__ __launch_bounds__(1024, 8) void fused_kernel(
    const float* __restrict__ x,
    const u16* __restrict__ kbf, const u16* __restrict__ vtbf,
    const float* __restrict__ qall,
    const int* __restrict__ perm, const int* __restrict__ ssort,
    const u16* __restrict__ outT, const float* __restrict__ out_b,
    const u16* __restrict__ bandT, const float* __restrict__ band_b,
    const u16* __restrict__ modT, const float* __restrict__ mod_b,
    const u16* __restrict__ hvT, const float* __restrict__ hv_b,
    const float* __restrict__ outl_W, const float* __restrict__ outl_b,
    float* __restrict__ out)
{
    const int bid = blockIdx.x;
    const int b   = bid >> 8;
    const int sp0 = (bid & 255) * 16;
    const int t   = threadIdx.x;
    const int wid = t >> 6, lane = t & 63;
    const int quad = lane >> 4, l16 = lane & 15;

    __shared__ __align__(16) u16 q_bf[16 * 136];
    __shared__ __align__(16) u16 gam_lds[32 * 72];
    __shared__ __align__(16) u16 P_bf[32 * PFP];
    __shared__ __align__(16) unsigned char regionA[PFP * 16 * 4];
    __shared__ __align__(16) u16 o_lds[16 * 136];
    __shared__ float fin[256];
    __shared__ float sh_xc[64];
    __shared__ int sh_pq[16], sh_s[16];

    float* P_f32 = (float*)regionA;
    float* o_part = (float*)regionA;
    u16* modu_lds = (u16*)regionA;
    u16* s01_lds  = (u16*)(regionA + 16 * 264 * 2);

    if (t < 16) { sh_pq[t] = perm[sp0 + t]; sh_s[t] = ssort[sp0 + t]; }
    __syncthreads();

    {   // stage q (bf16 A-rows) and grid coords
        int m = t >> 6, d = (t & 63) * 2;
        float2 qv = *(const float2*)&qall[(size_t)sh_pq[m] * 128 + d];
        unsigned int pk = (unsigned int)f2bf(qv.x) | ((unsigned int)f2bf(qv.y) << 16);
        *(unsigned int*)&q_bf[m * 136 + d] = pk;
    }
    if (t < 64) sh_xc[t] = x[(size_t)sh_pq[t >> 2] * 4 + (t & 3)];
    __syncthreads();

    // layer gammas (sorted order)
    #pragma unroll
    for (int j = 0; j < 2; j++) {
        int e = t * 2 + j;
        int l = e >> 10, g = (e >> 6) & 15, f = e & 63;
        int c = f >> 4, jj = f & 15, oi = jj & 7;
        float om = (float)(10.0 * exp((double)oi * (l ? K_OM1 : K_OM0)));
        float arg = PI_F * sh_xc[g * 4 + c] * om;
        gam_lds[(l * 16 + g) * 72 + f] = f2bf((jj < 8) ? sinf(arg) : cosf(arg));
    }

    const int u0    = sh_s[0] & ~7;
    const int ncols = min((sh_s[15] + 128 - u0 + 31) & ~31, NCMAX);
    const int nsub  = ncols >> 4;
    const int nkc   = ncols >> 5;

    // attention: heads sequential (scores MFMA -> masked softmax)
    #pragma unroll
    for (int h = 0; h < 2; h++) {
        s16x8 aq0 = *(const s16x8*)&q_bf[l16 * 136 + h * 64 + quad * 8];
        s16x8 aq1 = *(const s16x8*)&q_bf[l16 * 136 + h * 64 + 32 + quad * 8];
        for (int sub = wid; sub < nsub; sub += 16) {
            f32x4 acc = (f32x4){0.f, 0.f, 0.f, 0.f};
            size_t krow = (size_t)(b * 1024 + u0 + sub * 16 + l16) * 128 + h * 64 + quad * 8;
            s16x8 b0 = *(const s16x8*)&kbf[krow];
            s16x8 b1 = *(const s16x8*)&kbf[krow + 32];
            acc = __builtin_amdgcn_mfma_f32_16x16x32_bf16(aq0, b0, acc, 0, 0, 0);
            acc = __builtin_amdgcn_mfma_f32_16x16x32_bf16(aq1, b1, acc, 0, 0, 0);
            #pragma unroll
            for (int r = 0; r < 4; r++)
                P_f32[(quad * 4 + r) * PFP + sub * 16 + l16] = acc[r];
        }
        __syncthreads();
        {   // masked softmax: wave = sorted query g
            int g = wid;
            int sg = sh_s[g];
            float vals[5]; int ok[5];
            float mx = -1e30f;
            #pragma unroll
            for (int i = 0; i < 5; i++) {
                int c = lane + 64 * i;
                float v = P_f32[g * PFP + c] * 0.125f;
                int key = u0 + c;
                int o2 = (c < ncols) && (key >= sg) && (key < sg + 128);
                vals[i] = v; ok[i] = o2;
                if (o2) mx = fmaxf(mx, v);
            }
            #pragma unroll
            for (int off = 1; off < 64; off <<= 1) mx = fmaxf(mx, __shfl_xor(mx, off));
            float sum = 0.f, e5[5];
            #pragma unroll
            for (int i = 0; i < 5; i++) {
                float e = ok[i] ? expf(vals[i] - mx) : 0.f;
                e5[i] = e; sum += e;
            }
            #pragma unroll
            for (int off = 1; off < 64; off <<= 1) sum += __shfl_xor(sum, off);
            float inv = 1.f / sum;
            #pragma unroll
            for (int i = 0; i < 5; i++) {
                int c = lane + 64 * i;
                if (c < ncols) P_bf[(h * 16 + g) * PFP + c] = f2bf(e5[i] * inv);
            }
        }
        __syncthreads();
    }

    // P @ V (MFMA): wave = (col-subtile, K-half)
    {
        int n0 = (wid & 7) * 16;
        int hh = n0 >> 6;
        int khalf = wid >> 3;
        int nk2 = (nkc + 1) >> 1;
        int k0 = khalf ? nk2 : 0;
        int k1 = khalf ? nkc : nk2;
        f32x4 acc = (f32x4){0.f, 0.f, 0.f, 0.f};
        for (int kc = k0; kc < k1; kc++) {
            s16x8 a = *(const s16x8*)&P_bf[(hh * 16 + l16) * PFP + kc * 32 + quad * 8];
            int koff = u0 + kc * 32 + quad * 8;
            koff = min(koff, 1016);   // clamp pure-garbage chunks (P=0 there)
            s16x8 bfr = *(const s16x8*)&vtbf[(size_t)(b * 128 + n0 + l16) * 1024 + koff];
            acc = __builtin_amdgcn_mfma_f32_16x16x32_bf16(a, bfr, acc, 0, 0, 0);
        }
        #pragma unroll
        for (int r = 0; r < 4; r++)
            o_part[(khalf * 16 + quad * 4 + r) * 128 + n0 + l16] = acc[r];
    }
    __syncthreads();

    {   // o assembly: combine K-halves -> o_lds bf16
        int m = t >> 6, j2 = (t & 63) * 2;
        float v0 = o_part[m * 128 + j2]     + o_part[(16 + m) * 128 + j2];
        float v1 = o_part[m * 128 + j2 + 1] + o_part[(16 + m) * 128 + j2 + 1];
        unsigned int pk = (unsigned int)f2bf(v0) | ((unsigned int)f2bf(v1) << 16);
        *(unsigned int*)&o_lds[m * 136 + j2] = pk;
    }
    __syncthreads();

    // ---------------- MFMA MLP: 16 waves x 16 cols ----------------
    const int n0 = wid * 16;
    float m0f[4];

    {   // modulation = o @ out_W + out_b (K=128)
        f32x4 acc = (f32x4){0.f, 0.f, 0.f, 0.f};
        #pragma unroll
        for (int kc = 0; kc < 4; kc++) {
            s16x8 a = *(const s16x8*)&o_lds[l16 * 136 + kc * 32 + quad * 8];
            s16x8 bfr = *(const s16x8*)&outT[(size_t)(n0 + l16) * 128 + kc * 32 + quad * 8];
            acc = __builtin_amdgcn_mfma_f32_16x16x32_bf16(a, bfr, acc, 0, 0, 0);
        }
        int col = n0 + l16;
        float bias = out_b[col];
        #pragma unroll
        for (int r = 0; r < 4; r++)
            modu_lds[(quad * 4 + r) * 264 + col] = f2bf(acc[r] + bias);
    }
    __syncthreads();

    #pragma unroll
    for (int l = 0; l < 2; l++) {
        f32x4 acc1 = (f32x4){0.f, 0.f, 0.f, 0.f};
        f32x4 acc2 = (f32x4){0.f, 0.f, 0.f, 0.f};
        #pragma unroll
        for (int kc = 0; kc < 2; kc++) {
            s16x8 a = *(const s16x8*)&gam_lds[(l * 16 + l16) * 72 + kc * 32 + quad * 8];
            s16x8 bfr = *(const s16x8*)&bandT[(size_t)(n0 + l16) * 128 + l * 64 + kc * 32 + quad * 8];
            acc1 = __builtin_amdgcn_mfma_f32_16x16x32_bf16(a, bfr, acc1, 0, 0, 0);
        }
        #pragma unroll
        for (int kc = 0; kc < 8; kc++) {
            s16x8 a = *(const s16x8*)&modu_lds[l16 * 264 + kc * 32 + quad * 8];
            s16x8 bfr = *(const s16x8*)&modT[(size_t)(n0 + l16) * 512 + l * 256 + kc * 32 + quad * 8];
            acc2 = __builtin_amdgcn_mfma_f32_16x16x32_bf16(a, bfr, acc2, 0, 0, 0);
        }
        int col = n0 + l16;
        float bb = band_b[l * 256 + col];
        float mb = mod_b[l * 256 + col];
        #pragma unroll
        for (int r = 0; r < 4; r++) {
            float hval = fmaxf(acc1[r] + bb, 0.f);
            float mval = fmaxf(hval + acc2[r] + mb, 0.f);
            if (l == 0) m0f[r] = mval;
            else s01_lds[(quad * 4 + r) * 264 + col] = f2bf(m0f[r] + mval);
        }
    }
    __syncthreads();

    {   // h_v1 = relu(s01 @ hv_W + hv_b) + scalar head
        f32x4 acc = (f32x4){0.f, 0.f, 0.f, 0.f};
        #pragma unroll
        for (int kc = 0; kc < 8; kc++) {
            s16x8 a = *(const s16x8*)&s01_lds[l16 * 264 + kc * 32 + quad * 8];
            s16x8 bfr = *(const s16x8*)&hvT[(size_t)(n0 + l16) * 256 + kc * 32 + quad * 8];
            acc = __builtin_amdgcn_mfma_f32_16x16x32_bf16(a, bfr, acc, 0, 0, 0);
        }
        int col = n0 + l16;
        float w0 = outl_W[col], w1 = outl_W[256 + col], hb = hv_b[col];
        #pragma unroll
        for (int r = 0; r < 4; r++) {
            float hvv = fmaxf(acc[r] + hb, 0.f);
            float pv = m0f[r] * w0 + hvv * w1;
            #pragma unroll
            for (int off = 1; off < 16; off <<= 1) pv += __shfl_xor(pv, off);
            if (l16 == 0) fin[wid * 16 + quad * 4 + r] = pv;
        }
    }
    __syncthreads();
    if (t < 16) {
        float s2 = outl_b[0] + outl_b[1];
        #pragma unroll
        for (int w = 0; w < 16; w++) s2 += fin[w * 16 + t];
        out[(size_t)b * QN + sh_pq[t]] = s2;   // scatter by permutation
    }
}

// ---------------------------------------------------------------------------
extern "C" void kernel_launch(void* const* d_in, const int* in_sizes, int n_in,
                              void* d_out, int out_size, void* d_ws, size_t ws_size,
                              hipStream_t stream)
{
    const float* x       = (const float*)d_in[0];
    const float* tokens  = (const float*)d_in[1];
    const float* query_W = (const float*)d_in[2];
    const float* query_b = (const float*)d_in[3];
    const float* q_W     = (const float*)d_in[4];
    const float* kv_W    = (const float*)d_in[5];
    const float* out_W   = (const float*)d_in[6];
    const float* out_b   = (const float*)d_in[7];
    const float* band_W  = (const float*)d_in[8];
    const float* band_b  = (const float*)d_in[9];
    const float* mod_W   = (const float*)d_in[10];
    const float* mod_b   = (const float*)d_in[11];
    const float* hv_W    = (const float*)d_in[12];
    const float* hv_b    = (const float*)d_in[13];
    const float* outl_W  = (const float*)d_in[14];
    const float* outl_b  = (const float*)d_in[15];
    const int*   gD      = (const int*)d_in[16];
    const int*   gH      = (const int*)d_in[17];
    const int*   gW      = (const int*)d_in[18];
    const int*   gT      = (const int*)d_in[19];

    float* ws   = (float*)d_ws;
    float* qall = ws;                               // 4096*128 fp32
    u16* wb = (u16*)(ws + 524288);
    u16* kbf   = wb;                                // 2*1024*128 bf16
    u16* vtbf  = wb + 262144;                       // 2*128*1024 bf16
    u16* outT  = wb + 524288;                       // 32768
    u16* bandT = wb + 557056;                       // 32768
    u16* modT  = wb + 589824;                       // 131072
    u16* hvT   = wb + 720896;                       // 65536
    int* perm  = (int*)(wb + 786432);               // 4096 ints
    int* ssort = perm + 4096;                       // 4096 ints
    float* out = (float*)d_out;

    prep_kernel<<<449, 1024, 0, stream>>>(tokens, kv_W, x, query_W, query_b, q_W,
                                          out_W, band_W, mod_W, hv_W,
                                          gD, gH, gW, gT,
                                          qall, kbf, vtbf, outT, bandT, modT, hvT,
                                          perm, ssort);
    fused_kernel<<<512, 1024, 0, stream>>>(x, kbf, vtbf, qall, perm, ssort,
        outT, out_b, bandT, band_b, modT, mod_b, hvT, hv_b,
        outl_W, outl_b, out);
}

// Round 11
// 130.041 us; speedup vs baseline: 2.6137x; 1.1215x over previous
//
#include <hip/hip_runtime.h>
#include <math.h>

// Problem constants (match reference setup_inputs)
#define BN     2
#define QN     4096
#define LN     1024
#define TOPKN  128
#define PI_F   3.14159265358979323846f

// ln(12.8)/7 and ln(3.2)/7 — omegas = 10*exp(i*K), matches jnp.logspace to ~1e-7 rel
#define K_OM0  0.3642064529893673
#define K_OM1  0.1661644014008115

// union-window capacity (keys) and padded pitch for score/P buffers
#define NCMAX  320
#define PFP    328

typedef __attribute__((ext_vector_type(8))) short  s16x8;
typedef __attribute__((ext_vector_type(4))) short  s16x4;
typedef __attribute__((ext_vector_type(4))) float  f32x4;
typedef unsigned short u16;

__device__ __forceinline__ u16 f2bf(float f) {
    unsigned int u = __float_as_uint(f);
    u = (u + 0x7FFFu + ((u >> 16) & 1u)) >> 16;   // RNE
    return (u16)u;
}

// Tiled B-operand layouts: one wave MFMA-fragment load = contiguous memory.
// Weights wT: [n/16][k/32][n%16][k%32]  (wave load spans 1024B contiguous)
__device__ __forceinline__ size_t wtile(int n, int k, int K) {
    return (size_t)((n >> 4) * (K >> 5) + (k >> 5)) * 512 + (n & 15) * 32 + (k & 31);
}
// K cache: [b][l/16][d/8][l%16][d%8]  (256B contiguous per quad)
__device__ __forceinline__ size_t kidx(int b, int l, int d) {
    return (((size_t)(b * 64 + (l >> 4)) * 16 + (d >> 3)) * 16 + (l & 15)) * 8 + (d & 7);
}
// V cache: [b][n/16][k/8][n%16][k%8]  (256B contiguous per quad)
__device__ __forceinline__ size_t vidx(int b, int n, int k) {
    return (((size_t)(b * 8 + (n >> 4)) * 128 + (k >> 3)) * 16 + (n & 15)) * 8 + (k & 7);
}

// ---------------------------------------------------------------------------
// Launch 1: prep, 449 blocks x 1024 threads. Role dispatch:
//   [0,64)    kv path: 32 token rows/block; K -> kbf (tiled), V -> vtbf (tiled).
//   [64,192)  q path: 32 queries/block; gamma -> xq -> q (fp32 qall).
//   [192,448) transpose out/band/mod/hv to tiled bf16.
//   448       counting sort of queries by window start s -> perm, ssort.
// ---------------------------------------------------------------------------
struct KvS { u16 tok[32 * 264]; u16 stage[256 * 40]; float vtile[128][40]; };
struct QS  { float shx[128]; u16 gam[32 * 72]; u16 xq[32 * 264]; u16 stage[256 * 40]; };
struct TrS { float tile[32][33]; };
struct SoS { int hist[1024]; int cur[1024]; };
union PrepS { KvS kv; QS q; TrS tr; SoS so; };

__global__ __launch_bounds__(1024) void prep_kernel(
    const float* __restrict__ tokens, const float* __restrict__ kv_W,
    const float* __restrict__ x, const float* __restrict__ query_W,
    const float* __restrict__ query_b, const float* __restrict__ q_W,
    const float* __restrict__ outW, const float* __restrict__ bandW,
    const float* __restrict__ modW, const float* __restrict__ hvW,
    const int* __restrict__ gDp, const int* __restrict__ gHp,
    const int* __restrict__ gWp, const int* __restrict__ gTp,
    float* __restrict__ qall, u16* __restrict__ kbf, u16* __restrict__ vtbf,
    u16* __restrict__ outT, u16* __restrict__ bandT,
    u16* __restrict__ modT, u16* __restrict__ hvT,
    int* __restrict__ perm, int* __restrict__ ssort)
{
    __shared__ __align__(16) PrepS sm;
    const int bid = blockIdx.x;
    const int t   = threadIdx.x;
    const int wid = t >> 6, lane = t & 63;
    const int quad = lane >> 4, l16 = lane & 15;

    if (bid < 64) {
        // ---- kv path: 32 token rows/block, 16 waves ----
        int l0 = bid * 32;
        int b = l0 >> 10, lloc = l0 & 1023;
        #pragma unroll
        for (int i = 0; i < 8; i++) {
            int idx = i * 1024 + t; int row = idx >> 8, col = idx & 255;
            sm.kv.tok[row * 264 + col] = f2bf(tokens[(size_t)(l0 + row) * 256 + col]);
        }
        int m0 = (wid & 1) * 16;
        int c0 = (wid >> 1) * 32;
        f32x4 acc[2];
        acc[0] = (f32x4){0.f, 0.f, 0.f, 0.f};
        acc[1] = (f32x4){0.f, 0.f, 0.f, 0.f};
        for (int kc = 0; kc < 8; kc++) {
            __syncthreads();
            #pragma unroll
            for (int i = 0; i < 8; i++) {
                int idx = i * 1024 + t; int k = idx >> 8, n = idx & 255;
                sm.kv.stage[n * 40 + k] = f2bf(kv_W[(size_t)(kc * 32 + k) * 256 + n]);
            }
            __syncthreads();
            s16x8 a = *(const s16x8*)&sm.kv.tok[(m0 + l16) * 264 + kc * 32 + quad * 8];
            #pragma unroll
            for (int sub = 0; sub < 2; sub++) {
                s16x8 bfr = *(const s16x8*)&sm.kv.stage[(c0 + sub * 16 + l16) * 40 + quad * 8];
                acc[sub] = __builtin_amdgcn_mfma_f32_16x16x32_bf16(a, bfr, acc[sub], 0, 0, 0);
            }
        }
        #pragma unroll
        for (int sub = 0; sub < 2; sub++) {
            int col = c0 + sub * 16 + l16;
            if (col < 128) {
                #pragma unroll
                for (int r = 0; r < 4; r++) {
                    int lg = l0 + m0 + quad * 4 + r;
                    kbf[kidx(lg >> 10, lg & 1023, col)] = f2bf(acc[sub][r]);
                }
            } else {
                #pragma unroll
                for (int r = 0; r < 4; r++)
                    sm.kv.vtile[col - 128][m0 + quad * 4 + r] = acc[sub][r];
            }
        }
        __syncthreads();
        {   // vtbf (tiled): 4 bf16 per thread, 8B store within one k-chunk
            int col = t >> 3, rg = (t & 7) * 4;
            float4 v4 = *(const float4*)&sm.kv.vtile[col][rg];
            s16x4 pk;
            pk[0] = (short)f2bf(v4.x); pk[1] = (short)f2bf(v4.y);
            pk[2] = (short)f2bf(v4.z); pk[3] = (short)f2bf(v4.w);
            *(s16x4*)&vtbf[vidx(b, col, lloc + rg)] = pk;
        }
    } else if (bid < 192) {
        // ---- q path: 32 queries/block, 16 waves ----
        int p0 = (bid - 64) * 32;
        if (t < 128) sm.q.shx[t] = x[p0 * 4 + t];
        __syncthreads();
        #pragma unroll
        for (int j = 0; j < 2; j++) {
            int e = t * 2 + j;
            int g = e >> 6, f = e & 63;
            int c = f >> 4, jj = f & 15, oi = jj & 7;
            float om = (float)(10.0 * exp((double)oi * K_OM0));
            float arg = PI_F * sm.q.shx[g * 4 + c] * om;
            sm.q.gam[g * 72 + f] = f2bf((jj < 8) ? sinf(arg) : cosf(arg));
        }
        int m0 = (wid & 1) * 16;
        {   // stage 1: xq = relu(gamma @ query_W + b)
            int c0 = (wid >> 1) * 32;
            f32x4 acc[2];
            acc[0] = (f32x4){0.f, 0.f, 0.f, 0.f};
            acc[1] = (f32x4){0.f, 0.f, 0.f, 0.f};
            for (int kc = 0; kc < 2; kc++) {
                __syncthreads();
                #pragma unroll
                for (int i = 0; i < 8; i++) {
                    int idx = i * 1024 + t; int k = idx >> 8, n = idx & 255;
                    sm.q.stage[n * 40 + k] = f2bf(query_W[(size_t)(kc * 32 + k) * 256 + n]);
                }
                __syncthreads();
                s16x8 a = *(const s16x8*)&sm.q.gam[(m0 + l16) * 72 + kc * 32 + quad * 8];
                #pragma unroll
                for (int sub = 0; sub < 2; sub++) {
                    s16x8 bfr = *(const s16x8*)&sm.q.stage[(c0 + sub * 16 + l16) * 40 + quad * 8];
                    acc[sub] = __builtin_amdgcn_mfma_f32_16x16x32_bf16(a, bfr, acc[sub], 0, 0, 0);
                }
            }
            #pragma unroll
            for (int sub = 0; sub < 2; sub++) {
                int col = c0 + sub * 16 + l16;
                float bias = query_b[col];
                #pragma unroll
                for (int r = 0; r < 4; r++)
                    sm.q.xq[(m0 + quad * 4 + r) * 264 + col] = f2bf(fmaxf(acc[sub][r] + bias, 0.f));
            }
        }
        {   // stage 2: q = xq @ q_W
            int n0q = (wid >> 1) * 16;
            f32x4 acc2 = (f32x4){0.f, 0.f, 0.f, 0.f};
            for (int kc = 0; kc < 8; kc++) {
                __syncthreads();
                #pragma unroll
                for (int i = 0; i < 4; i++) {
                    int idx = i * 1024 + t; int k = idx >> 7, n = idx & 127;
                    sm.q.stage[n * 40 + k] = f2bf(q_W[(size_t)(kc * 32 + k) * 128 + n]);
                }
                __syncthreads();
                s16x8 a = *(const s16x8*)&sm.q.xq[(m0 + l16) * 264 + kc * 32 + quad * 8];
                s16x8 bfr = *(const s16x8*)&sm.q.stage[(n0q + l16) * 40 + quad * 8];
                acc2 = __builtin_amdgcn_mfma_f32_16x16x32_bf16(a, bfr, acc2, 0, 0, 0);
            }
            #pragma unroll
            for (int r = 0; r < 4; r++)
                qall[(size_t)(p0 + m0 + quad * 4 + r) * 128 + n0q + l16] = acc2[r];
        }
    } else if (bid < 448) {
        // ---- transpose path: one 32x32 tile/block, tiled dest ----
        int bid2 = bid - 192;
        const float* src; u16* dst; int K, N, lt;
        if      (bid2 < 32)  { src = outW;  dst = outT;  K = 128; N = 256; lt = bid2; }
        else if (bid2 < 64)  { src = bandW; dst = bandT; K = 128; N = 256; lt = bid2 - 32; }
        else if (bid2 < 192) { src = modW;  dst = modT;  K = 512; N = 256; lt = bid2 - 64; }
        else                 { src = hvW;   dst = hvT;   K = 256; N = 256; lt = bid2 - 192; }
        int tk = K >> 5;
        int ktile = lt % tk, nt = lt / tk;
        int k0 = ktile * 32, n0 = nt * 32;
        int tx = t & 31, ty = (t >> 5) & 31;
        sm.tr.tile[ty][tx] = src[(size_t)(k0 + ty) * N + n0 + tx];
        __syncthreads();
        dst[wtile(n0 + ty, k0 + tx, K)] = f2bf(sm.tr.tile[tx][ty]);
    } else {
        // ---- sort path: counting sort by window start, 1024 threads ----
        int gD = gDp[0], gH = gHp[0], gW = gWp[0], gT = gTp[0];
        int Ng = gD * gH * gW * gT;
        sm.so.hist[t] = 0;
        __syncthreads();
        int sarr[4];
        #pragma unroll
        for (int i = 0; i < 4; i++) {
            int q = i * 1024 + t;
            float4 xv = *(const float4*)&x[q * 4];
            int zi = (int)(xv.x * (float)gD);
            int yi = (int)(xv.y * (float)gH);
            int xi = (int)(xv.z * (float)gW);
            int ti = (int)(xv.w * (float)gT);
            int idx = ((ti * gD + zi) * gH + yi) * gW + xi;
            float tt = (float)idx / (float)Ng;
            int s = (int)ceilf(tt * (float)LN - ((float)(TOPKN / 2) + 0.5f));
            s = min(max(s, 0), LN - TOPKN);
            sarr[i] = s;
            atomicAdd(&sm.so.hist[s], 1);
        }
        __syncthreads();
        int cnt = sm.so.hist[t];
        sm.so.cur[t] = cnt;
        __syncthreads();
        for (int off = 1; off < 1024; off <<= 1) {
            int u = (t >= off) ? sm.so.cur[t - off] : 0;
            __syncthreads();
            sm.so.cur[t] += u;
            __syncthreads();
        }
        int excl = sm.so.cur[t] - cnt;
        __syncthreads();
        sm.so.hist[t] = excl;   // reuse hist as placement cursor
        __syncthreads();
        #pragma unroll
        for (int i = 0; i < 4; i++) {
            int q = i * 1024 + t;
            int pos = atomicAdd(&sm.so.hist[sarr[i]], 1);
            perm[pos] = q;
            ssort[pos] = sarr[i];
        }
    }
}

// ---------------------------------------------------------------------------
// Launch 2: fused. 512 blocks x 1024 threads, 2 blocks/CU. 16 SORTED queries
// per block; attention = dense MFMA GEMMs over the union window (tiled K/V)
// with per-query masking; MLP = verified MFMA chain on tiled weights.
// ---------------------------------------------------------------------------
__global__ __launch_bounds__(1024, 8) void fused_kernel(
    const float* __restrict__ x,
    const u16* __restrict__ kbf, const u16* __restrict__ vtbf,
    const float* __restrict__ qall,
    const int* __restrict__ perm, const int* __restrict__ ssort,
    const u16* __restrict__ outT, const float* __restrict__ out_b,
    const u16* __restrict__ bandT, const float* __restrict__ band_b,
    const u16* __restrict__ modT, const float* __restrict__ mod_b,
    const u16* __restrict__ hvT, const float* __restrict__ hv_b,
    const float* __restrict__ outl_W, const float* __restrict__ outl_b,
    float* __restrict__ out)
{
    const int bid = blockIdx.x;
    const int b   = bid >> 8;
    const int sp0 = (bid & 255) * 16;
    const int t   = threadIdx.x;
    const int wid = t >> 6, lane = t & 63;
    const int quad = lane >> 4, l16 = lane & 15;

    __shared__ __align__(16) u16 q_bf[16 * 136];
    __shared__ __align__(16) u16 gam_lds[32 * 72];
    __shared__ __align__(16) u16 P_bf[32 * PFP];
    __shared__ __align__(16) unsigned char regionA[PFP * 16 * 4];
    __shared__ __align__(16) u16 o_lds[16 * 136];
    __shared__ float fin[256];
    __shared__ float sh_xc[64];
    __shared__ int sh_pq[16], sh_s[16];

    float* P_f32 = (float*)regionA;
    float* o_part = (float*)regionA;
    u16* modu_lds = (u16*)regionA;
    u16* s01_lds  = (u16*)(regionA + 16 * 264 * 2);

    if (t < 16) { sh_pq[t] = perm[sp0 + t]; sh_s[t] = ssort[sp0 + t]; }
    __syncthreads();

    {   // stage q (bf16 A-rows) and grid coords
        int m = t >> 6, d = (t & 63) * 2;
        float2 qv = *(const float2*)&qall[(size_t)sh_pq[m] * 128 + d];
        unsigned int pk = (unsigned int)f2bf(qv.x) | ((unsigned int)f2bf(qv.y) << 16);
        *(unsigned int*)&q_bf[m * 136 + d] = pk;
    }
    if (t < 64) sh_xc[t] = x[(size_t)sh_pq[t >> 2] * 4 + (t & 3)];
    __syncthreads();

    // layer gammas (sorted order)
    #pragma unroll
    for (int j = 0; j < 2; j++) {
        int e = t * 2 + j;
        int l = e >> 10, g = (e >> 6) & 15, f = e & 63;
        int c = f >> 4, jj = f & 15, oi = jj & 7;
        float om = (float)(10.0 * exp((double)oi * (l ? K_OM1 : K_OM0)));
        float arg = PI_F * sh_xc[g * 4 + c] * om;
        gam_lds[(l * 16 + g) * 72 + f] = f2bf((jj < 8) ? sinf(arg) : cosf(arg));
    }

    const int u0    = sh_s[0] & ~15;           // 16-aligned for K tiling
    const int ncols = min((sh_s[15] + 128 - u0 + 31) & ~31, NCMAX);
    const int nsub  = ncols >> 4;
    const int nkc   = ncols >> 5;

    // attention: heads sequential (scores MFMA -> masked softmax)
    #pragma unroll
    for (int h = 0; h < 2; h++) {
        s16x8 aq0 = *(const s16x8*)&q_bf[l16 * 136 + h * 64 + quad * 8];
        s16x8 aq1 = *(const s16x8*)&q_bf[l16 * 136 + h * 64 + 32 + quad * 8];
        for (int sub = wid; sub < nsub; sub += 16) {
            f32x4 acc = (f32x4){0.f, 0.f, 0.f, 0.f};
            int lrow = u0 + sub * 16 + l16;
            s16x8 b0 = *(const s16x8*)&kbf[kidx(b, lrow, h * 64 + quad * 8)];
            s16x8 b1 = *(const s16x8*)&kbf[kidx(b, lrow, h * 64 + 32 + quad * 8)];
            acc = __builtin_amdgcn_mfma_f32_16x16x32_bf16(aq0, b0, acc, 0, 0, 0);
            acc = __builtin_amdgcn_mfma_f32_16x16x32_bf16(aq1, b1, acc, 0, 0, 0);
            #pragma unroll
            for (int r = 0; r < 4; r++)
                P_f32[(quad * 4 + r) * PFP + sub * 16 + l16] = acc[r];
        }
        __syncthreads();
        {   // masked softmax: wave = sorted query g
            int g = wid;
            int sg = sh_s[g];
            float vals[5]; int ok[5];
            float mx = -1e30f;
            #pragma unroll
            for (int i = 0; i < 5; i++) {
                int c = lane + 64 * i;
                float v = P_f32[g * PFP + c] * 0.125f;
                int key = u0 + c;
                int o2 = (c < ncols) && (key >= sg) && (key < sg + 128);
                vals[i] = v; ok[i] = o2;
                if (o2) mx = fmaxf(mx, v);
            }
            #pragma unroll
            for (int off = 1; off < 64; off <<= 1) mx = fmaxf(mx, __shfl_xor(mx, off));
            float sum = 0.f, e5[5];
            #pragma unroll
            for (int i = 0; i < 5; i++) {
                float e = ok[i] ? expf(vals[i] - mx) : 0.f;
                e5[i] = e; sum += e;
            }
            #pragma unroll
            for (int off = 1; off < 64; off <<= 1) sum += __shfl_xor(sum, off);
            float inv = 1.f / sum;
            #pragma unroll
            for (int i = 0; i < 5; i++) {
                int c = lane + 64 * i;
                if (c < ncols) P_bf[(h * 16 + g) * PFP + c] = f2bf(e5[i] * inv);
            }
        }
        __syncthreads();
    }

    // P @ V (MFMA): wave = (col-subtile, K-half), tiled V loads
    {
        int n0 = (wid & 7) * 16;
        int hh = n0 >> 6;
        int khalf = wid >> 3;
        int nk2 = (nkc + 1) >> 1;
        int k0 = khalf ? nk2 : 0;
        int k1 = khalf ? nkc : nk2;
        f32x4 acc = (f32x4){0.f, 0.f, 0.f, 0.f};
        for (int kc = k0; kc < k1; kc++) {
            s16x8 a = *(const s16x8*)&P_bf[(hh * 16 + l16) * PFP + kc * 32 + quad * 8];
            int koff = u0 + kc * 32 + quad * 8;
            koff = min(koff, 1016);   // clamp pure-garbage chunks (P=0 there)
            s16x8 bfr = *(const s16x8*)&vtbf[vidx(b, n0 + l16, koff)];
            acc = __builtin_amdgcn_mfma_f32_16x16x32_bf16(a, bfr, acc, 0, 0, 0);
        }
        #pragma unroll
        for (int r = 0; r < 4; r++)
            o_part[(khalf * 16 + quad * 4 + r) * 128 + n0 + l16] = acc[r];
    }
    __syncthreads();

    {   // o assembly: combine K-halves -> o_lds bf16
        int m = t >> 6, j2 = (t & 63) * 2;
        float v0 = o_part[m * 128 + j2]     + o_part[(16 + m) * 128 + j2];
        float v1 = o_part[m * 128 + j2 + 1] + o_part[(16 + m) * 128 + j2 + 1];
        unsigned int pk = (unsigned int)f2bf(v0) | ((unsigned int)f2bf(v1) << 16);
        *(unsigned int*)&o_lds[m * 136 + j2] = pk;
    }
    __syncthreads();

    // ---------------- MFMA MLP: 16 waves x 16 cols, tiled weights ----------------
    const int n0 = wid * 16;
    float m0f[4];

    {   // modulation = o @ out_W + out_b (K=128)
        f32x4 acc = (f32x4){0.f, 0.f, 0.f, 0.f};
        #pragma unroll
        for (int kc = 0; kc < 4; kc++) {
            s16x8 a = *(const s16x8*)&o_lds[l16 * 136 + kc * 32 + quad * 8];
            s16x8 bfr = *(const s16x8*)&outT[wtile(n0 + l16, kc * 32 + quad * 8, 128)];
            acc = __builtin_amdgcn_mfma_f32_16x16x32_bf16(a, bfr, acc, 0, 0, 0);
        }
        int col = n0 + l16;
        float bias = out_b[col];
        #pragma unroll
        for (int r = 0; r < 4; r++)
            modu_lds[(quad * 4 + r) * 264 + col] = f2bf(acc[r] + bias);
    }
    __syncthreads();

    #pragma unroll
    for (int l = 0; l < 2; l++) {
        f32x4 acc1 = (f32x4){0.f, 0.f, 0.f, 0.f};
        f32x4 acc2 = (f32x4){0.f, 0.f, 0.f, 0.f};
        #pragma unroll
        for (int kc = 0; kc < 2; kc++) {
            s16x8 a = *(const s16x8*)&gam_lds[(l * 16 + l16) * 72 + kc * 32 + quad * 8];
            s16x8 bfr = *(const s16x8*)&bandT[wtile(n0 + l16, l * 64 + kc * 32 + quad * 8, 128)];
            acc1 = __builtin_amdgcn_mfma_f32_16x16x32_bf16(a, bfr, acc1, 0, 0, 0);
        }
        #pragma unroll
        for (int kc = 0; kc < 8; kc++) {
            s16x8 a = *(const s16x8*)&modu_lds[l16 * 264 + kc * 32 + quad * 8];
            s16x8 bfr = *(const s16x8*)&modT[wtile(n0 + l16, l * 256 + kc * 32 + quad * 8, 512)];
            acc2 = __builtin_amdgcn_mfma_f32_16x16x32_bf16(a, bfr, acc2, 0, 0, 0);
        }
        int col = n0 + l16;
        float bb = band_b[l * 256 + col];
        float mb = mod_b[l * 256 + col];
        #pragma unroll
        for (int r = 0; r < 4; r++) {
            float hval = fmaxf(acc1[r] + bb, 0.f);
            float mval = fmaxf(hval + acc2[r] + mb, 0.f);
            if (l == 0) m0f[r] = mval;
            else s01_lds[(quad * 4 + r) * 264 + col] = f2bf(m0f[r] + mval);
        }
    }
    __syncthreads();

    {   // h_v1 = relu(s01 @ hv_W + hv_b) + scalar head
        f32x4 acc = (f32x4){0.f, 0.f, 0.f, 0.f};
        #pragma unroll
        for (int kc = 0; kc < 8; kc++) {
            s16x8 a = *(const s16x8*)&s01_lds[l16 * 264 + kc * 32 + quad * 8];
            s16x8 bfr = *(const s16x8*)&hvT[wtile(n0 + l16, kc * 32 + quad * 8, 256)];
            acc = __builtin_amdgcn_mfma_f32_16x16x32_bf16(a, bfr, acc, 0, 0, 0);
        }
        int col = n0 + l16;
        float w0 = outl_W[col], w1 = outl_W[256 + col], hb = hv_b[col];
        #pragma unroll
        for (int r = 0; r < 4; r++) {
            float hvv = fmaxf(acc[r] + hb, 0.f);
            float pv = m0f[r] * w0 + hvv * w1;
            #pragma unroll
            for (int off = 1; off < 16; off <<= 1) pv += __shfl_xor(pv, off);
            if (l16 == 0) fin[wid * 16 + quad * 4 + r] = pv;
        }
    }
    __syncthreads();
    if (t < 16) {
        float s2 = outl_b[0] + outl_b[1];
        #pragma unroll
        for (int w = 0; w < 16; w++) s2 += fin[w * 16 + t];
        out[(size_t)b * QN + sh_pq[t]] = s2;   // scatter by permutation
    }
}

// ---------------------------------------------------------------------------
extern "C" void kernel_launch(void* const* d_in, const int* in_sizes, int n_in,
                              void* d_out, int out_size, void* d_ws, size_t ws_size,
                              hipStream_t stream)
{
    const float* x       = (const float*)d_in[0];
    const float* tokens  = (const float*)d_in[1];
    const float* query_W = (const float*)d_in[2];
    const float* query_b = (const float*)d_in[3];
    const float* q_W     = (const float*)d_in[4];
    const float* kv_W    = (const float*)d_in[5];
    const float* out_W   = (const float*)d_in[6];
    const float* out_b   = (const float*)d_in[7];
    const float* band_W  = (const float*)d_in[8];
    const float* band_b  = (const float*)d_in[9];
    const float* mod_W   = (const float*)d_in[10];
    const float* mod_b   = (const float*)d_in[11];
    const float* hv_W    = (const float*)d_in[12];
    const float* hv_b    = (const float*)d_in[13];
    const float* outl_W  = (const float*)d_in[14];
    const float* outl_b  = (const float*)d_in[15];
    const int*   gD      = (const int*)d_in[16];
    const int*   gH      = (const int*)d_in[17];
    const int*   gW      = (const int*)d_in[18];
    const int*   gT      = (const int*)d_in[19];

    float* ws   = (float*)d_ws;
    float* qall = ws;                               // 4096*128 fp32
    u16* wb = (u16*)(ws + 524288);
    u16* kbf   = wb;                                // 2*1024*128 bf16 (tiled)
    u16* vtbf  = wb + 262144;                       // 2*128*1024 bf16 (tiled)
    u16* outT  = wb + 524288;                       // 32768 (tiled)
    u16* bandT = wb + 557056;                       // 32768 (tiled)
    u16* modT  = wb + 589824;                       // 131072 (tiled)
    u16* hvT   = wb + 720896;                       // 65536 (tiled)
    int* perm  = (int*)(wb + 786432);               // 4096 ints
    int* ssort = perm + 4096;                       // 4096 ints
    float* out = (float*)d_out;

    prep_kernel<<<449, 1024, 0, stream>>>(tokens, kv_W, x, query_W, query_b, q_W,
                                          out_W, band_W, mod_W, hv_W,
                                          gD, gH, gW, gT,
                                          qall, kbf, vtbf, outT, bandT, modT, hvT,
                                          perm, ssort);
    fused_kernel<<<512, 1024, 0, stream>>>(x, kbf, vtbf, qall, perm, ssort,
        outT, out_b, bandT, band_b, modT, mod_b, hvT, hv_b,
        outl_W, outl_b, out);
}

// Round 12
// 128.083 us; speedup vs baseline: 2.6536x; 1.0153x over previous
//
#include <hip/hip_runtime.h>
#include <math.h>

// Problem constants (match reference setup_inputs)
#define BN     2
#define QN     4096
#define LN     1024
#define TOPKN  128
#define PI_F   3.14159265358979323846f

// ln(12.8)/7 and ln(3.2)/7 — omegas = 10*exp(i*K), matches jnp.logspace to ~1e-7 rel
#define K_OM0  0.3642064529893673
#define K_OM1  0.1661644014008115

// union-window capacity (keys) and padded pitch for score/P buffers
#define NCMAX  320
#define PFP    328

typedef __attribute__((ext_vector_type(8))) short  s16x8;
typedef __attribute__((ext_vector_type(4))) short  s16x4;
typedef __attribute__((ext_vector_type(4))) float  f32x4;
typedef unsigned short u16;

__device__ __forceinline__ u16 f2bf(float f) {
    unsigned int u = __float_as_uint(f);
    u = (u + 0x7FFFu + ((u >> 16) & 1u)) >> 16;   // RNE
    return (u16)u;
}

// Tiled B-operand layouts: one wave MFMA-fragment load = contiguous memory.
// Weights wT: [n/16][k/32][n%16][k%32]  (wave load spans 1024B contiguous)
__device__ __forceinline__ size_t wtile(int n, int k, int K) {
    return (size_t)((n >> 4) * (K >> 5) + (k >> 5)) * 512 + (n & 15) * 32 + (k & 31);
}
// K cache: [b][l/16][d/8][l%16][d%8]  (256B contiguous per quad)
__device__ __forceinline__ size_t kidx(int b, int l, int d) {
    return (((size_t)(b * 64 + (l >> 4)) * 16 + (d >> 3)) * 16 + (l & 15)) * 8 + (d & 7);
}
// V cache: [b][n/16][k/8][n%16][k%8]  (256B contiguous per quad)
__device__ __forceinline__ size_t vidx(int b, int n, int k) {
    return (((size_t)(b * 8 + (n >> 4)) * 128 + (k >> 3)) * 16 + (n & 15)) * 8 + (k & 7);
}

// ---------------------------------------------------------------------------
// Launch 1: prep, 449 blocks x 1024 threads (verbatim from round 11, passed).
// ---------------------------------------------------------------------------
struct KvS { u16 tok[32 * 264]; u16 stage[256 * 40]; float vtile[128][40]; };
struct QS  { float shx[128]; u16 gam[32 * 72]; u16 xq[32 * 264]; u16 stage[256 * 40]; };
struct TrS { float tile[32][33]; };
struct SoS { int hist[1024]; int cur[1024]; };
union PrepS { KvS kv; QS q; TrS tr; SoS so; };

__global__ __launch_bounds__(1024) void prep_kernel(
    const float* __restrict__ tokens, const float* __restrict__ kv_W,
    const float* __restrict__ x, const float* __restrict__ query_W,
    const float* __restrict__ query_b, const float* __restrict__ q_W,
    const float* __restrict__ outW, const float* __restrict__ bandW,
    const float* __restrict__ modW, const float* __restrict__ hvW,
    const int* __restrict__ gDp, const int* __restrict__ gHp,
    const int* __restrict__ gWp, const int* __restrict__ gTp,
    float* __restrict__ qall, u16* __restrict__ kbf, u16* __restrict__ vtbf,
    u16* __restrict__ outT, u16* __restrict__ bandT,
    u16* __restrict__ modT, u16* __restrict__ hvT,
    int* __restrict__ perm, int* __restrict__ ssort)
{
    __shared__ __align__(16) PrepS sm;
    const int bid = blockIdx.x;
    const int t   = threadIdx.x;
    const int wid = t >> 6, lane = t & 63;
    const int quad = lane >> 4, l16 = lane & 15;

    if (bid < 64) {
        // ---- kv path: 32 token rows/block, 16 waves ----
        int l0 = bid * 32;
        int b = l0 >> 10, lloc = l0 & 1023;
        #pragma unroll
        for (int i = 0; i < 8; i++) {
            int idx = i * 1024 + t; int row = idx >> 8, col = idx & 255;
            sm.kv.tok[row * 264 + col] = f2bf(tokens[(size_t)(l0 + row) * 256 + col]);
        }
        int m0 = (wid & 1) * 16;
        int c0 = (wid >> 1) * 32;
        f32x4 acc[2];
        acc[0] = (f32x4){0.f, 0.f, 0.f, 0.f};
        acc[1] = (f32x4){0.f, 0.f, 0.f, 0.f};
        for (int kc = 0; kc < 8; kc++) {
            __syncthreads();
            #pragma unroll
            for (int i = 0; i < 8; i++) {
                int idx = i * 1024 + t; int k = idx >> 8, n = idx & 255;
                sm.kv.stage[n * 40 + k] = f2bf(kv_W[(size_t)(kc * 32 + k) * 256 + n]);
            }
            __syncthreads();
            s16x8 a = *(const s16x8*)&sm.kv.tok[(m0 + l16) * 264 + kc * 32 + quad * 8];
            #pragma unroll
            for (int sub = 0; sub < 2; sub++) {
                s16x8 bfr = *(const s16x8*)&sm.kv.stage[(c0 + sub * 16 + l16) * 40 + quad * 8];
                acc[sub] = __builtin_amdgcn_mfma_f32_16x16x32_bf16(a, bfr, acc[sub], 0, 0, 0);
            }
        }
        #pragma unroll
        for (int sub = 0; sub < 2; sub++) {
            int col = c0 + sub * 16 + l16;
            if (col < 128) {
                #pragma unroll
                for (int r = 0; r < 4; r++) {
                    int lg = l0 + m0 + quad * 4 + r;
                    kbf[kidx(lg >> 10, lg & 1023, col)] = f2bf(acc[sub][r]);
                }
            } else {
                #pragma unroll
                for (int r = 0; r < 4; r++)
                    sm.kv.vtile[col - 128][m0 + quad * 4 + r] = acc[sub][r];
            }
        }
        __syncthreads();
        {   // vtbf (tiled): 4 bf16 per thread, 8B store within one k-chunk
            int col = t >> 3, rg = (t & 7) * 4;
            float4 v4 = *(const float4*)&sm.kv.vtile[col][rg];
            s16x4 pk;
            pk[0] = (short)f2bf(v4.x); pk[1] = (short)f2bf(v4.y);
            pk[2] = (short)f2bf(v4.z); pk[3] = (short)f2bf(v4.w);
            *(s16x4*)&vtbf[vidx(b, col, lloc + rg)] = pk;
        }
    } else if (bid < 192) {
        // ---- q path: 32 queries/block, 16 waves ----
        int p0 = (bid - 64) * 32;
        if (t < 128) sm.q.shx[t] = x[p0 * 4 + t];
        __syncthreads();
        #pragma unroll
        for (int j = 0; j < 2; j++) {
            int e = t * 2 + j;
            int g = e >> 6, f = e & 63;
            int c = f >> 4, jj = f & 15, oi = jj & 7;
            float om = (float)(10.0 * exp((double)oi * K_OM0));
            float arg = PI_F * sm.q.shx[g * 4 + c] * om;
            sm.q.gam[g * 72 + f] = f2bf((jj < 8) ? sinf(arg) : cosf(arg));
        }
        int m0 = (wid & 1) * 16;
        {   // stage 1: xq = relu(gamma @ query_W + b)
            int c0 = (wid >> 1) * 32;
            f32x4 acc[2];
            acc[0] = (f32x4){0.f, 0.f, 0.f, 0.f};
            acc[1] = (f32x4){0.f, 0.f, 0.f, 0.f};
            for (int kc = 0; kc < 2; kc++) {
                __syncthreads();
                #pragma unroll
                for (int i = 0; i < 8; i++) {
                    int idx = i * 1024 + t; int k = idx >> 8, n = idx & 255;
                    sm.q.stage[n * 40 + k] = f2bf(query_W[(size_t)(kc * 32 + k) * 256 + n]);
                }
                __syncthreads();
                s16x8 a = *(const s16x8*)&sm.q.gam[(m0 + l16) * 72 + kc * 32 + quad * 8];
                #pragma unroll
                for (int sub = 0; sub < 2; sub++) {
                    s16x8 bfr = *(const s16x8*)&sm.q.stage[(c0 + sub * 16 + l16) * 40 + quad * 8];
                    acc[sub] = __builtin_amdgcn_mfma_f32_16x16x32_bf16(a, bfr, acc[sub], 0, 0, 0);
                }
            }
            #pragma unroll
            for (int sub = 0; sub < 2; sub++) {
                int col = c0 + sub * 16 + l16;
                float bias = query_b[col];
                #pragma unroll
                for (int r = 0; r < 4; r++)
                    sm.q.xq[(m0 + quad * 4 + r) * 264 + col] = f2bf(fmaxf(acc[sub][r] + bias, 0.f));
            }
        }
        {   // stage 2: q = xq @ q_W
            int n0q = (wid >> 1) * 16;
            f32x4 acc2 = (f32x4){0.f, 0.f, 0.f, 0.f};
            for (int kc = 0; kc < 8; kc++) {
                __syncthreads();
                #pragma unroll
                for (int i = 0; i < 4; i++) {
                    int idx = i * 1024 + t; int k = idx >> 7, n = idx & 127;
                    sm.q.stage[n * 40 + k] = f2bf(q_W[(size_t)(kc * 32 + k) * 128 + n]);
                }
                __syncthreads();
                s16x8 a = *(const s16x8*)&sm.q.xq[(m0 + l16) * 264 + kc * 32 + quad * 8];
                s16x8 bfr = *(const s16x8*)&sm.q.stage[(n0q + l16) * 40 + quad * 8];
                acc2 = __builtin_amdgcn_mfma_f32_16x16x32_bf16(a, bfr, acc2, 0, 0, 0);
            }
            #pragma unroll
            for (int r = 0; r < 4; r++)
                qall[(size_t)(p0 + m0 + quad * 4 + r) * 128 + n0q + l16] = acc2[r];
        }
    } else if (bid < 448) {
        // ---- transpose path: one 32x32 tile/block, tiled dest ----
        int bid2 = bid - 192;
        const float* src; u16* dst; int K, N, lt;
        if      (bid2 < 32)  { src = outW;  dst = outT;  K = 128; N = 256; lt = bid2; }
        else if (bid2 < 64)  { src = bandW; dst = bandT; K = 128; N = 256; lt = bid2 - 32; }
        else if (bid2 < 192) { src = modW;  dst = modT;  K = 512; N = 256; lt = bid2 - 64; }
        else                 { src = hvW;   dst = hvT;   K = 256; N = 256; lt = bid2 - 192; }
        int tk = K >> 5;
        int ktile = lt % tk, nt = lt / tk;
        int k0 = ktile * 32, n0 = nt * 32;
        int tx = t & 31, ty = (t >> 5) & 31;
        sm.tr.tile[ty][tx] = src[(size_t)(k0 + ty) * N + n0 + tx];
        __syncthreads();
        dst[wtile(n0 + ty, k0 + tx, K)] = f2bf(sm.tr.tile[tx][ty]);
    } else {
        // ---- sort path: counting sort by window start, 1024 threads ----
        int gD = gDp[0], gH = gHp[0], gW = gWp[0], gT = gTp[0];
        int Ng = gD * gH * gW * gT;
        sm.so.hist[t] = 0;
        __syncthreads();
        int sarr[4];
        #pragma unroll
        for (int i = 0; i < 4; i++) {
            int q = i * 1024 + t;
            float4 xv = *(const float4*)&x[q * 4];
            int zi = (int)(xv.x * (float)gD);
            int yi = (int)(xv.y * (float)gH);
            int xi = (int)(xv.z * (float)gW);
            int ti = (int)(xv.w * (float)gT);
            int idx = ((ti * gD + zi) * gH + yi) * gW + xi;
            float tt = (float)idx / (float)Ng;
            int s = (int)ceilf(tt * (float)LN - ((float)(TOPKN / 2) + 0.5f));
            s = min(max(s, 0), LN - TOPKN);
            sarr[i] = s;
            atomicAdd(&sm.so.hist[s], 1);
        }
        __syncthreads();
        int cnt = sm.so.hist[t];
        sm.so.cur[t] = cnt;
        __syncthreads();
        for (int off = 1; off < 1024; off <<= 1) {
            int u = (t >= off) ? sm.so.cur[t - off] : 0;
            __syncthreads();
            sm.so.cur[t] += u;
            __syncthreads();
        }
        int excl = sm.so.cur[t] - cnt;
        __syncthreads();
        sm.so.hist[t] = excl;   // reuse hist as placement cursor
        __syncthreads();
        #pragma unroll
        for (int i = 0; i < 4; i++) {
            int q = i * 1024 + t;
            int pos = atomicAdd(&sm.so.hist[sarr[i]], 1);
            perm[pos] = q;
            ssort[pos] = sarr[i];
        }
    }
}

// ---------------------------------------------------------------------------
// Launch 2: fused. 512 blocks x 1024 threads, 2 blocks/CU. 16 SORTED queries.
// Restructured: single scores pass (both heads) into one 32xPFP fp32 buffer;
// softmax writes bf16 P in-place (per-row, hazard-free); P@V = one wave per
// 16-col tile over the full k-range (no split/combine). 8 barriers (was 11).
// ---------------------------------------------------------------------------
__global__ __launch_bounds__(1024, 8) void fused_kernel(
    const float* __restrict__ x,
    const u16* __restrict__ kbf, const u16* __restrict__ vtbf,
    const float* __restrict__ qall,
    const int* __restrict__ perm, const int* __restrict__ ssort,
    const u16* __restrict__ outT, const float* __restrict__ out_b,
    const u16* __restrict__ bandT, const float* __restrict__ band_b,
    const u16* __restrict__ modT, const float* __restrict__ mod_b,
    const u16* __restrict__ hvT, const float* __restrict__ hv_b,
    const float* __restrict__ outl_W, const float* __restrict__ outl_b,
    float* __restrict__ out)
{
    const int bid = blockIdx.x;
    const int b   = bid >> 8;
    const int sp0 = (bid & 255) * 16;
    const int t   = threadIdx.x;
    const int wid = t >> 6, lane = t & 63;
    const int quad = lane >> 4, l16 = lane & 15;

    __shared__ __align__(16) u16 q_bf[16 * 136];
    __shared__ __align__(16) u16 gam_lds[32 * 72];
    __shared__ __align__(16) float scores32[32 * PFP];   // scores / P_bf / modu+s01
    __shared__ __align__(16) u16 o_lds[16 * 136];
    __shared__ float fin[256];
    __shared__ float sh_xc[64];
    __shared__ int sh_pq[16], sh_s[16];

    u16* modu_lds = (u16*)scores32;
    u16* s01_lds  = ((u16*)scores32) + 16 * 264;

    if (t < 16) { sh_pq[t] = perm[sp0 + t]; sh_s[t] = ssort[sp0 + t]; }
    __syncthreads();                                             // b1

    {   // stage q (bf16 A-rows) and grid coords
        int m = t >> 6, d = (t & 63) * 2;
        float2 qv = *(const float2*)&qall[(size_t)sh_pq[m] * 128 + d];
        unsigned int pk = (unsigned int)f2bf(qv.x) | ((unsigned int)f2bf(qv.y) << 16);
        *(unsigned int*)&q_bf[m * 136 + d] = pk;
    }
    if (t < 64) sh_xc[t] = x[(size_t)sh_pq[t >> 2] * 4 + (t & 3)];
    __syncthreads();                                             // b2

    // layer gammas (sorted order) — consumed after b6, any barrier covers
    #pragma unroll
    for (int j = 0; j < 2; j++) {
        int e = t * 2 + j;
        int l = e >> 10, g = (e >> 6) & 15, f = e & 63;
        int c = f >> 4, jj = f & 15, oi = jj & 7;
        float om = (float)(10.0 * exp((double)oi * (l ? K_OM1 : K_OM0)));
        float arg = PI_F * sh_xc[g * 4 + c] * om;
        gam_lds[(l * 16 + g) * 72 + f] = f2bf((jj < 8) ? sinf(arg) : cosf(arg));
    }

    const int u0    = sh_s[0] & ~15;           // 16-aligned for K tiling
    const int ncols = min((sh_s[15] + 128 - u0 + 31) & ~31, NCMAX);
    const int nsub  = ncols >> 4;
    const int nkc   = ncols >> 5;

    // ---- scores, both heads in one pass: job = (head, subtile) ----
    {
        s16x8 aq00 = *(const s16x8*)&q_bf[l16 * 136 + quad * 8];
        s16x8 aq01 = *(const s16x8*)&q_bf[l16 * 136 + 32 + quad * 8];
        s16x8 aq10 = *(const s16x8*)&q_bf[l16 * 136 + 64 + quad * 8];
        s16x8 aq11 = *(const s16x8*)&q_bf[l16 * 136 + 96 + quad * 8];
        for (int j = wid; j < 2 * nsub; j += 16) {
            int h = (j >= nsub) ? 1 : 0;
            int sub = j - h * nsub;
            int lrow = u0 + sub * 16 + l16;
            f32x4 acc = (f32x4){0.f, 0.f, 0.f, 0.f};
            s16x8 b0 = *(const s16x8*)&kbf[kidx(b, lrow, h * 64 + quad * 8)];
            s16x8 b1 = *(const s16x8*)&kbf[kidx(b, lrow, h * 64 + 32 + quad * 8)];
            acc = __builtin_amdgcn_mfma_f32_16x16x32_bf16(h ? aq10 : aq00, b0, acc, 0, 0, 0);
            acc = __builtin_amdgcn_mfma_f32_16x16x32_bf16(h ? aq11 : aq01, b1, acc, 0, 0, 0);
            #pragma unroll
            for (int r = 0; r < 4; r++)
                scores32[(h * 16 + quad * 4 + r) * PFP + sub * 16 + l16] = acc[r];
        }
    }
    __syncthreads();                                             // b3

    // ---- masked softmax, both rows per wave; bf16 P written in-place ----
    {
        int g = wid;
        int sg = sh_s[g];
        #pragma unroll
        for (int rr = 0; rr < 2; rr++) {
            int row = g + rr * 16;
            float vals[5]; int ok[5];
            float mx = -1e30f;
            #pragma unroll
            for (int i = 0; i < 5; i++) {
                int c = lane + 64 * i;
                float v = scores32[row * PFP + c] * 0.125f;
                int key = u0 + c;
                int o2 = (c < ncols) && (key >= sg) && (key < sg + 128);
                vals[i] = v; ok[i] = o2;
                if (o2) mx = fmaxf(mx, v);
            }
            #pragma unroll
            for (int off = 1; off < 64; off <<= 1) mx = fmaxf(mx, __shfl_xor(mx, off));
            float sum = 0.f, e5[5];
            #pragma unroll
            for (int i = 0; i < 5; i++) {
                float e = ok[i] ? expf(vals[i] - mx) : 0.f;
                e5[i] = e; sum += e;
            }
            #pragma unroll
            for (int off = 1; off < 64; off <<= 1) sum += __shfl_xor(sum, off);
            float inv = 1.f / sum;
            u16* prow = (u16*)&scores32[row * PFP];   // in-place bf16 P (row-local)
            #pragma unroll
            for (int i = 0; i < 5; i++) {
                int c = lane + 64 * i;
                if (c < ncols) prow[c] = f2bf(e5[i] * inv);
            }
        }
    }
    __syncthreads();                                             // b4

    // ---- P @ V (MFMA): one wave per 16-col tile, full k-range ----
    if (wid < 8) {
        int n0 = wid * 16;
        int hh = n0 >> 6;
        const u16* prow = (const u16*)&scores32[(hh * 16 + l16) * PFP];
        f32x4 acc = (f32x4){0.f, 0.f, 0.f, 0.f};
        for (int kc = 0; kc < nkc; kc++) {
            s16x8 a = *(const s16x8*)&prow[kc * 32 + quad * 8];
            int koff = u0 + kc * 32 + quad * 8;
            koff = min(koff, 1016);   // clamp pure-garbage chunks (P=0 there)
            s16x8 bfr = *(const s16x8*)&vtbf[vidx(b, n0 + l16, koff)];
            acc = __builtin_amdgcn_mfma_f32_16x16x32_bf16(a, bfr, acc, 0, 0, 0);
        }
        #pragma unroll
        for (int r = 0; r < 4; r++)
            o_lds[(quad * 4 + r) * 136 + n0 + l16] = f2bf(acc[r]);
    }
    __syncthreads();                                             // b5

    // ---------------- MFMA MLP: 16 waves x 16 cols, tiled weights ----------------
    const int n0 = wid * 16;
    float m0f[4];

    {   // modulation = o @ out_W + out_b (K=128)
        f32x4 acc = (f32x4){0.f, 0.f, 0.f, 0.f};
        #pragma unroll
        for (int kc = 0; kc < 4; kc++) {
            s16x8 a = *(const s16x8*)&o_lds[l16 * 136 + kc * 32 + quad * 8];
            s16x8 bfr = *(const s16x8*)&outT[wtile(n0 + l16, kc * 32 + quad * 8, 128)];
            acc = __builtin_amdgcn_mfma_f32_16x16x32_bf16(a, bfr, acc, 0, 0, 0);
        }
        int col = n0 + l16;
        float bias = out_b[col];
        #pragma unroll
        for (int r = 0; r < 4; r++)
            modu_lds[(quad * 4 + r) * 264 + col] = f2bf(acc[r] + bias);
    }
    __syncthreads();                                             // b6

    #pragma unroll
    for (int l = 0; l < 2; l++) {
        f32x4 acc1 = (f32x4){0.f, 0.f, 0.f, 0.f};
        f32x4 acc2 = (f32x4){0.f, 0.f, 0.f, 0.f};
        #pragma unroll
        for (int kc = 0; kc < 2; kc++) {
            s16x8 a = *(const s16x8*)&gam_lds[(l * 16 + l16) * 72 + kc * 32 + quad * 8];
            s16x8 bfr = *(const s16x8*)&bandT[wtile(n0 + l16, l * 64 + kc * 32 + quad * 8, 128)];
            acc1 = __builtin_amdgcn_mfma_f32_16x16x32_bf16(a, bfr, acc1, 0, 0, 0);
        }
        #pragma unroll
        for (int kc = 0; kc < 8; kc++) {
            s16x8 a = *(const s16x8*)&modu_lds[l16 * 264 + kc * 32 + quad * 8];
            s16x8 bfr = *(const s16x8*)&modT[wtile(n0 + l16, l * 256 + kc * 32 + quad * 8, 512)];
            acc2 = __builtin_amdgcn_mfma_f32_16x16x32_bf16(a, bfr, acc2, 0, 0, 0);
        }
        int col = n0 + l16;
        float bb = band_b[l * 256 + col];
        float mb = mod_b[l * 256 + col];
        #pragma unroll
        for (int r = 0; r < 4; r++) {
            float hval = fmaxf(acc1[r] + bb, 0.f);
            float mval = fmaxf(hval + acc2[r] + mb, 0.f);
            if (l == 0) m0f[r] = mval;
            else s01_lds[(quad * 4 + r) * 264 + col] = f2bf(m0f[r] + mval);
        }
    }
    __syncthreads();                                             // b7

    {   // h_v1 = relu(s01 @ hv_W + hv_b) + scalar head
        f32x4 acc = (f32x4){0.f, 0.f, 0.f, 0.f};
        #pragma unroll
        for (int kc = 0; kc < 8; kc++) {
            s16x8 a = *(const s16x8*)&s01_lds[l16 * 264 + kc * 32 + quad * 8];
            s16x8 bfr = *(const s16x8*)&hvT[wtile(n0 + l16, kc * 32 + quad * 8, 256)];
            acc = __builtin_amdgcn_mfma_f32_16x16x32_bf16(a, bfr, acc, 0, 0, 0);
        }
        int col = n0 + l16;
        float w0 = outl_W[col], w1 = outl_W[256 + col], hb = hv_b[col];
        #pragma unroll
        for (int r = 0; r < 4; r++) {
            float hvv = fmaxf(acc[r] + hb, 0.f);
            float pv = m0f[r] * w0 + hvv * w1;
            #pragma unroll
            for (int off = 1; off < 16; off <<= 1) pv += __shfl_xor(pv, off);
            if (l16 == 0) fin[wid * 16 + quad * 4 + r] = pv;
        }
    }
    __syncthreads();                                             // b8
    if (t < 16) {
        float s2 = outl_b[0] + outl_b[1];
        #pragma unroll
        for (int w = 0; w < 16; w++) s2 += fin[w * 16 + t];
        out[(size_t)b * QN + sh_pq[t]] = s2;   // scatter by permutation
    }
}

// ---------------------------------------------------------------------------
extern "C" void kernel_launch(void* const* d_in, const int* in_sizes, int n_in,
                              void* d_out, int out_size, void* d_ws, size_t ws_size,
                              hipStream_t stream)
{
    const float* x       = (const float*)d_in[0];
    const float* tokens  = (const float*)d_in[1];
    const float* query_W = (const float*)d_in[2];
    const float* query_b = (const float*)d_in[3];
    const float* q_W     = (const float*)d_in[4];
    const float* kv_W    = (const float*)d_in[5];
    const float* out_W   = (const float*)d_in[6];
    const float* out_b   = (const float*)d_in[7];
    const float* band_W  = (const float*)d_in[8];
    const float* band_b  = (const float*)d_in[9];
    const float* mod_W   = (const float*)d_in[10];
    const float* mod_b   = (const float*)d_in[11];
    const float* hv_W    = (const float*)d_in[12];
    const float* hv_b    = (const float*)d_in[13];
    const float* outl_W  = (const float*)d_in[14];
    const float* outl_b  = (const float*)d_in[15];
    const int*   gD      = (const int*)d_in[16];
    const int*   gH      = (const int*)d_in[17];
    const int*   gW      = (const int*)d_in[18];
    const int*   gT      = (const int*)d_in[19];

    float* ws   = (float*)d_ws;
    float* qall = ws;                               // 4096*128 fp32
    u16* wb = (u16*)(ws + 524288);
    u16* kbf   = wb;                                // 2*1024*128 bf16 (tiled)
    u16* vtbf  = wb + 262144;                       // 2*128*1024 bf16 (tiled)
    u16* outT  = wb + 524288;                       // 32768 (tiled)
    u16* bandT = wb + 557056;                       // 32768 (tiled)
    u16* modT  = wb + 589824;                       // 131072 (tiled)
    u16* hvT   = wb + 720896;                       // 65536 (tiled)
    int* perm  = (int*)(wb + 786432);               // 4096 ints
    int* ssort = perm + 4096;                       // 4096 ints
    float* out = (float*)d_out;

    prep_kernel<<<449, 1024, 0, stream>>>(tokens, kv_W, x, query_W, query_b, q_W,
                                          out_W, band_W, mod_W, hv_W,
                                          gD, gH, gW, gT,
                                          qall, kbf, vtbf, outT, bandT, modT, hvT,
                                          perm, ssort);
    fused_kernel<<<512, 1024, 0, stream>>>(x, kbf, vtbf, qall, perm, ssort,
        outT, out_b, bandT, band_b, modT, mod_b, hvT, hv_b,
        outl_W, outl_b, out);
}